// Round 1
// baseline (1836.998 us; speedup 1.0000x reference)
//
#include <hip/hip_runtime.h>
#include <hip/hip_bf16.h>

#define NN 10000
#define NE 160000
#define INF 256
#define CH 512
#define NL 1440

// ---------------- degree histogram ----------------
__global__ void deg_kernel(const int* __restrict__ src, const int* __restrict__ dst,
                           int* __restrict__ deg_out, int* __restrict__ deg_in) {
    int e = blockIdx.x * 256 + threadIdx.x;
    if (e < NE) {
        atomicAdd(&deg_out[src[e]], 1);
        atomicAdd(&deg_in[dst[e]], 1);
    }
}

// ---------------- exclusive scan of deg_out -> offsets (single block) ----------------
__global__ __launch_bounds__(1024) void scan_kernel(const int* __restrict__ deg,
                                                    int* __restrict__ offsets,
                                                    int* __restrict__ cursor) {
    __shared__ int sums[1024];
    const int PER = 10;  // 1024*10 >= 10000
    int tid = threadIdx.x;
    int base = tid * PER;
    int local[PER];
    int s = 0;
    #pragma unroll
    for (int i = 0; i < PER; i++) {
        int v = (base + i < NN) ? deg[base + i] : 0;
        local[i] = s;
        s += v;
    }
    sums[tid] = s;
    __syncthreads();
    for (int off = 1; off < 1024; off <<= 1) {
        int v = (tid >= off) ? sums[tid - off] : 0;
        __syncthreads();
        sums[tid] += v;
        __syncthreads();
    }
    int prev = (tid > 0) ? sums[tid - 1] : 0;
    #pragma unroll
    for (int i = 0; i < PER; i++) {
        if (base + i < NN) {
            int o = prev + local[i];
            offsets[base + i] = o;
            cursor[base + i] = o;
        }
    }
    if (tid == 0) offsets[NN] = sums[1023];
}

// ---------------- counting-sort fill: CSR by src, with edge weights ----------------
__global__ void csr_kernel(const int* __restrict__ src, const int* __restrict__ dst,
                           const int* __restrict__ deg_out, const int* __restrict__ deg_in,
                           int* __restrict__ cursor, int* __restrict__ edge_dst,
                           float* __restrict__ edge_w) {
    int e = blockIdx.x * 256 + threadIdx.x;
    if (e < NE) {
        int s = src[e], d = dst[e];
        float dw = (float)max(deg_out[s], 1) * (float)max(deg_in[d], 1);
        float w = rsqrtf(dw);
        int pos = atomicAdd(&cursor[s], 1);
        edge_dst[pos] = d;
        edge_w[pos] = w;
    }
}

// ---------------- aggregation: out[u] = sum_{e in CSR[u]} w[e]*m[dst[e]] ----------------
__global__ __launch_bounds__(256) void aggregate_kernel(const float* __restrict__ m,
                                                        const int* __restrict__ offsets,
                                                        const int* __restrict__ edge_dst,
                                                        const float* __restrict__ edge_w,
                                                        float* __restrict__ out) {
    int u = blockIdx.x;
    int c = threadIdx.x;
    int beg = offsets[u], end = offsets[u + 1];
    float a0 = 0.f, a1 = 0.f;
    for (int e = beg; e < end; e++) {
        int d = edge_dst[e];
        float wt = edge_w[e];
        a0 += wt * m[(size_t)d * CH + c];
        a1 += wt * m[(size_t)d * CH + c + 256];
    }
    out[(size_t)u * CH + c] = a0;
    out[(size_t)u * CH + c + 256] = a1;
}

// ---------------- f32 tiled GEMM: C = A[MxK] @ B[KxN] (+C) (+bias) (relu) ----------------
// FLAGS: 1 = add existing C, 2 = add bias, 4 = relu
#define TM 128
#define TN 128
#define TK 16

template <int FLAGS>
__global__ __launch_bounds__(256) void gemm_f32(const float* __restrict__ A,
                                                const float* __restrict__ B,
                                                float* __restrict__ C,
                                                const float* __restrict__ bias,
                                                int M, int N, int K) {
    __shared__ float AsT[TK][TM];   // transposed A tile: AsT[k][m]
    __shared__ float Bs[TK][TN];

    int tid = threadIdx.x;
    int tx = tid & 15;       // N dim
    int ty = tid >> 4;       // M dim
    int m0 = blockIdx.y * TM;
    int n0 = blockIdx.x * TN;

    float acc[8][8];
    #pragma unroll
    for (int i = 0; i < 8; i++)
        #pragma unroll
        for (int j = 0; j < 8; j++) acc[i][j] = 0.f;

    // load mapping
    int lr = tid >> 1;          // 0..127  A tile row
    int lh = (tid & 1) * 8;     // 0 or 8  A tile col offset
    int brow = tid >> 4;        // 0..15   B tile row
    int bcol = (tid & 15) * 8;  // 0..120  B tile col

    for (int kc = 0; kc < K; kc += TK) {
        float4 a4_0, a4_1;
        if (m0 + lr < M) {
            const float* ap = &A[(size_t)(m0 + lr) * K + kc + lh];
            a4_0 = *(const float4*)(ap);
            a4_1 = *(const float4*)(ap + 4);
        } else {
            a4_0 = make_float4(0.f, 0.f, 0.f, 0.f);
            a4_1 = a4_0;
        }
        float4 b4_0, b4_1;
        {
            int col0 = n0 + bcol;
            const float* bp = &B[(size_t)(kc + brow) * N + col0];
            b4_0 = (col0 < N) ? *(const float4*)(bp) : make_float4(0.f, 0.f, 0.f, 0.f);
            b4_1 = (col0 + 4 < N) ? *(const float4*)(bp + 4) : make_float4(0.f, 0.f, 0.f, 0.f);
        }
        __syncthreads();
        AsT[lh + 0][lr] = a4_0.x;
        AsT[lh + 1][lr] = a4_0.y;
        AsT[lh + 2][lr] = a4_0.z;
        AsT[lh + 3][lr] = a4_0.w;
        AsT[lh + 4][lr] = a4_1.x;
        AsT[lh + 5][lr] = a4_1.y;
        AsT[lh + 6][lr] = a4_1.z;
        AsT[lh + 7][lr] = a4_1.w;
        *(float4*)&Bs[brow][bcol] = b4_0;
        *(float4*)&Bs[brow][bcol + 4] = b4_1;
        __syncthreads();

        #pragma unroll
        for (int kk = 0; kk < TK; kk++) {
            float4 a0 = *(const float4*)&AsT[kk][ty * 4];
            float4 a1 = *(const float4*)&AsT[kk][64 + ty * 4];
            float4 b0 = *(const float4*)&Bs[kk][tx * 4];
            float4 b1 = *(const float4*)&Bs[kk][64 + tx * 4];
            float av[8] = {a0.x, a0.y, a0.z, a0.w, a1.x, a1.y, a1.z, a1.w};
            float bv[8] = {b0.x, b0.y, b0.z, b0.w, b1.x, b1.y, b1.z, b1.w};
            #pragma unroll
            for (int i = 0; i < 8; i++)
                #pragma unroll
                for (int j = 0; j < 8; j++) acc[i][j] += av[i] * bv[j];
        }
    }

    // epilogue
    #pragma unroll
    for (int hi = 0; hi < 2; hi++) {
        #pragma unroll
        for (int i = 0; i < 4; i++) {
            int row = m0 + hi * 64 + ty * 4 + i;
            if (row >= M) continue;
            #pragma unroll
            for (int hj = 0; hj < 2; hj++) {
                int col = n0 + hj * 64 + tx * 4;
                if (col >= N) continue;  // col,N multiples of 4 -> full float4 valid
                float4 c;
                c.x = acc[hi * 4 + i][hj * 4 + 0];
                c.y = acc[hi * 4 + i][hj * 4 + 1];
                c.z = acc[hi * 4 + i][hj * 4 + 2];
                c.w = acc[hi * 4 + i][hj * 4 + 3];
                float* cp = &C[(size_t)row * N + col];
                if (FLAGS & 1) {
                    float4 o = *(const float4*)cp;
                    c.x += o.x; c.y += o.y; c.z += o.z; c.w += o.w;
                }
                if (FLAGS & 2) {
                    float4 bv = *(const float4*)&bias[col];
                    c.x += bv.x; c.y += bv.y; c.z += bv.z; c.w += bv.w;
                }
                if (FLAGS & 4) {
                    c.x = fmaxf(c.x, 0.f); c.y = fmaxf(c.y, 0.f);
                    c.z = fmaxf(c.z, 0.f); c.w = fmaxf(c.w, 0.f);
                }
                *(float4*)cp = c;
            }
        }
    }
}

// ---------------- host launch ----------------
extern "C" void kernel_launch(void* const* d_in, const int* in_sizes, int n_in,
                              void* d_out, int out_size, void* d_ws, size_t ws_size,
                              hipStream_t stream) {
    const float* x  = (const float*)d_in[0];
    const int* src  = (const int*)d_in[1];
    const int* dst  = (const int*)d_in[2];
    const float* W1 = (const float*)d_in[3];
    const float* V1 = (const float*)d_in[4];
    const float* b1 = (const float*)d_in[5];
    const float* Wk = (const float*)d_in[6];
    const float* Vk = (const float*)d_in[7];
    const float* bk = (const float*)d_in[8];
    const float* Wd = (const float*)d_in[9];
    const float* bd = (const float*)d_in[10];
    float* out = (float*)d_out;

    // workspace layout (all 16B aligned)
    int* deg_out  = (int*)d_ws;
    int* deg_in   = deg_out + 10240;
    int* offsets  = deg_in + 10240;     // NN+1
    int* cursor   = offsets + 10240;
    int* edge_dst = cursor + 10240;     // NE
    float* edge_w = (float*)(edge_dst + NE);
    float* mbuf   = edge_w + NE;
    float* h0     = mbuf + (size_t)NN * CH;
    float* h1     = h0 + (size_t)NN * CH;

    hipMemsetAsync(deg_out, 0, 2 * 10240 * sizeof(int), stream);

    deg_kernel<<<(NE + 255) / 256, 256, 0, stream>>>(src, dst, deg_out, deg_in);
    scan_kernel<<<1, 1024, 0, stream>>>(deg_out, offsets, cursor);
    csr_kernel<<<(NE + 255) / 256, 256, 0, stream>>>(src, dst, deg_out, deg_in,
                                                     cursor, edge_dst, edge_w);

    dim3 blk(256);
    dim3 g512((CH + TN - 1) / TN, (NN + TM - 1) / TM);
    dim3 gout((NL + TN - 1) / TN, (NN + TM - 1) / TM);

    // layer 1: h1 = relu(agg(x@W1) + x@V1 + b1)
    gemm_f32<0><<<g512, blk, 0, stream>>>(x, W1, mbuf, nullptr, NN, CH, INF);
    aggregate_kernel<<<NN, 256, 0, stream>>>(mbuf, offsets, edge_dst, edge_w, h1);
    gemm_f32<7><<<g512, blk, 0, stream>>>(x, V1, h1, b1, NN, CH, INF);

    float* h_cur = h1;
    float* h_next = h0;
    for (int i = 0; i < 6; i++) {
        const float* W = Wk + (size_t)i * CH * CH;
        const float* V = Vk + (size_t)i * CH * CH;
        const float* b = bk + (size_t)i * CH;
        gemm_f32<0><<<g512, blk, 0, stream>>>(h_cur, W, mbuf, nullptr, NN, CH, CH);
        aggregate_kernel<<<NN, 256, 0, stream>>>(mbuf, offsets, edge_dst, edge_w, h_next);
        gemm_f32<7><<<g512, blk, 0, stream>>>(h_cur, V, h_next, b, NN, CH, CH);
        float* t = h_cur; h_cur = h_next; h_next = t;
    }

    // output: out = h @ Wd + bd
    gemm_f32<2><<<gout, blk, 0, stream>>>(h_cur, Wd, out, bd, NN, NL, CH);
}

// Round 2
// 1442.832 us; speedup vs baseline: 1.2732x; 1.2732x over previous
//
#include <hip/hip_runtime.h>
#include <hip/hip_bf16.h>
#include <stdint.h>

#define NN 10000
#define NE 160000
#define INF 256
#define CH 512
#define NL 1440
#define MPAD 10112  // NN rounded up to 128

typedef __bf16 bf16;
typedef __attribute__((ext_vector_type(8))) bf16 bf16x8;
typedef __attribute__((ext_vector_type(4))) bf16 bf16x4;
typedef __attribute__((ext_vector_type(4))) float f32x4;

// CK-proven addrspace cast idiom for global_load_lds
__device__ __forceinline__ void gload16(const void* g, const void* l) {
    auto gp = reinterpret_cast<const __attribute__((address_space(1))) uint32_t*>(
        reinterpret_cast<uintptr_t>(g));
    auto lp = reinterpret_cast<__attribute__((address_space(3))) uint32_t*>(
        reinterpret_cast<uintptr_t>(l));
    __builtin_amdgcn_global_load_lds(gp, lp, 16, 0, 0);
}

// ---------------- graph prep ----------------
__global__ void deg_kernel(const int* __restrict__ src, const int* __restrict__ dst,
                           int* __restrict__ deg_out, int* __restrict__ deg_in) {
    int e = blockIdx.x * 256 + threadIdx.x;
    if (e < NE) {
        atomicAdd(&deg_out[src[e]], 1);
        atomicAdd(&deg_in[dst[e]], 1);
    }
}

__global__ __launch_bounds__(1024) void scan_kernel(const int* __restrict__ deg,
                                                    int* __restrict__ offsets,
                                                    int* __restrict__ cursor) {
    __shared__ int sums[1024];
    const int PER = 10;
    int tid = threadIdx.x;
    int base = tid * PER;
    int local[PER];
    int s = 0;
    #pragma unroll
    for (int i = 0; i < PER; i++) {
        int v = (base + i < NN) ? deg[base + i] : 0;
        local[i] = s;
        s += v;
    }
    sums[tid] = s;
    __syncthreads();
    for (int off = 1; off < 1024; off <<= 1) {
        int v = (tid >= off) ? sums[tid - off] : 0;
        __syncthreads();
        sums[tid] += v;
        __syncthreads();
    }
    int prev = (tid > 0) ? sums[tid - 1] : 0;
    #pragma unroll
    for (int i = 0; i < PER; i++) {
        if (base + i < NN) {
            int o = prev + local[i];
            offsets[base + i] = o;
            cursor[base + i] = o;
        }
    }
    if (tid == 0) offsets[NN] = sums[1023];
}

__global__ void csr_kernel(const int* __restrict__ src, const int* __restrict__ dst,
                           const int* __restrict__ deg_out, const int* __restrict__ deg_in,
                           int* __restrict__ cursor, int* __restrict__ edge_dst,
                           float* __restrict__ edge_w) {
    int e = blockIdx.x * 256 + threadIdx.x;
    if (e < NE) {
        int s = src[e], d = dst[e];
        float dw = (float)max(deg_out[s], 1) * (float)max(deg_in[d], 1);
        float w = rsqrtf(dw);
        int pos = atomicAdd(&cursor[s], 1);
        edge_dst[pos] = d;
        edge_w[pos] = w;
    }
}

// ---------------- aggregation ----------------
__global__ __launch_bounds__(256) void aggregate_kernel(const float* __restrict__ m,
                                                        const int* __restrict__ offsets,
                                                        const int* __restrict__ edge_dst,
                                                        const float* __restrict__ edge_w,
                                                        float* __restrict__ out) {
    int u = blockIdx.x;
    int c = threadIdx.x;
    int beg = offsets[u], end = offsets[u + 1];
    float a0 = 0.f, a1 = 0.f;
    for (int e = beg; e < end; e++) {
        int d = edge_dst[e];
        float wt = edge_w[e];
        a0 += wt * m[(size_t)d * CH + c];
        a1 += wt * m[(size_t)d * CH + c + 256];
    }
    out[(size_t)u * CH + c] = a0;
    out[(size_t)u * CH + c + 256] = a1;
}

// ---------------- f32 -> split bf16 (hi|lo planes), row-major ----------------
__global__ void split_rows(const float* __restrict__ in, bf16* __restrict__ out,
                           int M, int K) {
    int idx = blockIdx.x * 256 + threadIdx.x;
    int tot = M * (K / 4);
    if (idx >= tot) return;
    int m = idx / (K / 4);
    int k4 = (idx % (K / 4)) * 4;
    float4 v = *(const float4*)&in[(size_t)m * K + k4];
    float vv[4] = {v.x, v.y, v.z, v.w};
    bf16x4 hi, lo;
    #pragma unroll
    for (int j = 0; j < 4; j++) {
        bf16 h = (bf16)vv[j];
        hi[j] = h;
        lo[j] = (bf16)(vv[j] - (float)h);
    }
    *(bf16x4*)&out[(size_t)m * 2 * K + k4] = hi;
    *(bf16x4*)&out[(size_t)m * 2 * K + K + k4] = lo;
}

// ---------------- W[K][N] f32 -> W3T[N][2K] bf16 (hi|lo planes) ----------------
__global__ void tsplit(const float* __restrict__ in, bf16* __restrict__ out,
                       int K, int N, size_t inStride, size_t outStride) {
    int z = blockIdx.z;
    in += (size_t)z * inStride;
    out += (size_t)z * outStride;
    int idx = blockIdx.x * 256 + threadIdx.x;
    int tot = N * (K / 8);
    if (idx >= tot) return;
    int kc = (idx / N) * 8;
    int n = idx % N;
    bf16x8 hi, lo;
    #pragma unroll
    for (int j = 0; j < 8; j++) {
        float v = in[(size_t)(kc + j) * N + n];
        bf16 h = (bf16)v;
        hi[j] = h;
        lo[j] = (bf16)(v - (float)h);
    }
    *(bf16x8*)&out[(size_t)n * 2 * K + kc] = hi;
    *(bf16x8*)&out[(size_t)n * 2 * K + K + kc] = lo;
}

// ---------------- split-bf16 MFMA GEMM ----------------
// Computes C = A @ B in ~f32 precision via triple-pass bf16 (K' = 3K).
// A3: [M][2K] bf16 (hi plane | lo plane), row stride 2K
// B3T: [N][2K] bf16 (hi plane | lo plane), row stride 2K
// FLAGS: 1 = add Cin, 2 = add bias, 4 = relu, 8 = write f32 Fout, 16 = write split Sout[M][2N]
template <int FLAGS>
__global__ __launch_bounds__(256) void gemm_bf16s(
    const bf16* __restrict__ A3, const bf16* __restrict__ B3T,
    const float* __restrict__ Cin, float* __restrict__ Fout,
    bf16* __restrict__ Sout, const float* __restrict__ bias,
    int M, int N, int K) {
    // LDS layout: unit u (16B = 8 bf16) = g*128 + row, g = k-subgroup (0..3)
    __shared__ bf16 ldsA[4096];  // 128 rows x 32 k'
    __shared__ bf16 ldsB[4096];  // 128 cols x 32 k'

    int tid = threadIdx.x;
    int lane = tid & 63, w = tid >> 6;
    int wm = w >> 1, wn = w & 1;
    int lr = lane & 15, lg = lane >> 4;
    int m0 = blockIdx.y * 128, n0 = blockIdx.x * 128;
    int K2 = 2 * K, K3 = 3 * K;

    f32x4 acc[4][4];
    #pragma unroll
    for (int i = 0; i < 4; i++)
        #pragma unroll
        for (int j = 0; j < 4; j++) {
            f32x4 z = {0.f, 0.f, 0.f, 0.f};
            acc[i][j] = z;
        }

    // staging unit indices (2 units per thread for each of A, B)
    int u0 = tid, u1 = tid + 256;
    int ag0 = u0 >> 7, ar0 = u0 & 127;
    int ag1 = u1 >> 7, ar1 = u1 & 127;

    const bf16* pa = ldsA + lg * 1024 + (wm * 64 + lr) * 8;
    const bf16* pb = ldsB + lg * 1024 + (wn * 64 + lr) * 8;

    for (int kc = 0; kc < K3; kc += 32) {
        int ka = (kc < K2) ? kc : kc - K2;  // A plane select (hi, lo, hi)
        int kb = (kc < K) ? kc : kc - K;    // B plane select (hi, hi, lo)
        gload16(A3 + (size_t)(m0 + ar0) * K2 + ka + ag0 * 8, ldsA + u0 * 8);
        gload16(A3 + (size_t)(m0 + ar1) * K2 + ka + ag1 * 8, ldsA + u1 * 8);
        gload16(B3T + (size_t)(n0 + ar0) * K2 + kb + ag0 * 8, ldsB + u0 * 8);
        gload16(B3T + (size_t)(n0 + ar1) * K2 + kb + ag1 * 8, ldsB + u1 * 8);
        __syncthreads();  // drains vmcnt before barrier -> LDS ready

        bf16x8 af[4], bfr[4];
        #pragma unroll
        for (int m = 0; m < 4; m++) af[m] = *(const bf16x8*)(pa + m * 128);
        #pragma unroll
        for (int n = 0; n < 4; n++) bfr[n] = *(const bf16x8*)(pb + n * 128);
        #pragma unroll
        for (int m = 0; m < 4; m++)
            #pragma unroll
            for (int n = 0; n < 4; n++)
                acc[m][n] = __builtin_amdgcn_mfma_f32_16x16x32_bf16(af[m], bfr[n],
                                                                   acc[m][n], 0, 0, 0);
        __syncthreads();  // compute done before next overwrite
    }

    // epilogue: C/D layout col = lane&15, row = (lane>>4)*4 + reg  [m89-verified]
    #pragma unroll
    for (int m = 0; m < 4; m++) {
        #pragma unroll
        for (int n = 0; n < 4; n++) {
            int grow0 = m0 + wm * 64 + m * 16 + lg * 4;
            int gcol = n0 + wn * 64 + n * 16 + lr;
            if (gcol >= N) continue;
            float bv = (FLAGS & 2) ? bias[gcol] : 0.f;
            #pragma unroll
            for (int r = 0; r < 4; r++) {
                int grow = grow0 + r;
                if (grow >= M) continue;
                float v = acc[m][n][r];
                if (FLAGS & 1) v += Cin[(size_t)grow * N + gcol];
                if (FLAGS & 2) v += bv;
                if (FLAGS & 4) v = fmaxf(v, 0.f);
                if (FLAGS & 8) Fout[(size_t)grow * N + gcol] = v;
                if (FLAGS & 16) {
                    bf16 h = (bf16)v;
                    Sout[(size_t)grow * (2 * N) + gcol] = h;
                    Sout[(size_t)grow * (2 * N) + N + gcol] = (bf16)(v - (float)h);
                }
            }
        }
    }
}

// ---------------- host launch ----------------
extern "C" void kernel_launch(void* const* d_in, const int* in_sizes, int n_in,
                              void* d_out, int out_size, void* d_ws, size_t ws_size,
                              hipStream_t stream) {
    const float* x  = (const float*)d_in[0];
    const int* src  = (const int*)d_in[1];
    const int* dst  = (const int*)d_in[2];
    const float* W1 = (const float*)d_in[3];
    const float* V1 = (const float*)d_in[4];
    const float* b1 = (const float*)d_in[5];
    const float* Wk = (const float*)d_in[6];
    const float* Vk = (const float*)d_in[7];
    const float* bk = (const float*)d_in[8];
    const float* Wd = (const float*)d_in[9];
    const float* bd = (const float*)d_in[10];

    // ws layout
    int* deg_out  = (int*)d_ws;
    int* deg_in   = deg_out + 10240;
    int* offsets  = deg_in + 10240;
    int* cursor   = offsets + 10240;
    int* edge_dst = cursor + 10240;
    float* edge_w = (float*)(edge_dst + NE);
    bf16* bufA    = (bf16*)(edge_w + NE);            // [MPAD][1024]
    bf16* bufB    = bufA + (size_t)MPAD * 1024;      // [MPAD][1024]
    bf16* w1t     = bufB + (size_t)MPAD * 1024;      // [512][512]
    bf16* v1t     = w1t + (size_t)512 * 512;         // [512][512]
    bf16* wkt     = v1t + (size_t)512 * 512;         // [6][512][1024]
    bf16* vkt     = wkt + (size_t)6 * 512 * 1024;    // [6][512][1024]
    bf16* wdt     = vkt + (size_t)6 * 512 * 1024;    // [1536][1024]

    // d_out doubles as f32 scratch (fully overwritten by the final GEMM)
    float* mbuf   = (float*)d_out;                   // [NN][CH]
    float* aggbuf = mbuf + (size_t)NN * CH;          // [NN][CH]
    float* out    = (float*)d_out;

    hipMemsetAsync(deg_out, 0, 2 * 10240 * sizeof(int), stream);
    deg_kernel<<<(NE + 255) / 256, 256, 0, stream>>>(src, dst, deg_out, deg_in);
    scan_kernel<<<1, 1024, 0, stream>>>(deg_out, offsets, cursor);
    csr_kernel<<<(NE + 255) / 256, 256, 0, stream>>>(src, dst, deg_out, deg_in,
                                                     cursor, edge_dst, edge_w);

    // conversions
    split_rows<<<(NN * (INF / 4) + 255) / 256, 256, 0, stream>>>(x, bufA, NN, INF);
    tsplit<<<dim3((512 * (INF / 8) + 255) / 256, 1, 1), 256, 0, stream>>>(
        W1, w1t, INF, 512, 0, 0);
    tsplit<<<dim3((512 * (INF / 8) + 255) / 256, 1, 1), 256, 0, stream>>>(
        V1, v1t, INF, 512, 0, 0);
    tsplit<<<dim3((512 * (CH / 8) + 255) / 256, 1, 6), 256, 0, stream>>>(
        Wk, wkt, CH, 512, (size_t)CH * 512, (size_t)512 * 1024);
    tsplit<<<dim3((512 * (CH / 8) + 255) / 256, 1, 6), 256, 0, stream>>>(
        Vk, vkt, CH, 512, (size_t)CH * 512, (size_t)512 * 1024);
    tsplit<<<dim3((NL * (CH / 8) + 255) / 256, 1, 1), 256, 0, stream>>>(
        Wd, wdt, CH, NL, 0, 0);

    dim3 blk(256);
    dim3 g512(4, 79);    // N=512 tiles x ceil(10000/128)
    dim3 gout(12, 79);   // N=1440 tiles

    // layer 1
    gemm_bf16s<8><<<g512, blk, 0, stream>>>(bufA, w1t, nullptr, mbuf, nullptr,
                                            nullptr, NN, CH, INF);
    aggregate_kernel<<<NN, 256, 0, stream>>>(mbuf, offsets, edge_dst, edge_w, aggbuf);
    gemm_bf16s<1 | 2 | 4 | 16><<<g512, blk, 0, stream>>>(bufA, v1t, aggbuf, nullptr,
                                                         bufB, b1, NN, CH, INF);

    bf16* cur = bufB;
    bf16* nxt = bufA;
    for (int i = 0; i < 6; i++) {
        const bf16* W = wkt + (size_t)i * 512 * 1024;
        const bf16* V = vkt + (size_t)i * 512 * 1024;
        gemm_bf16s<8><<<g512, blk, 0, stream>>>(cur, W, nullptr, mbuf, nullptr,
                                                nullptr, NN, CH, CH);
        aggregate_kernel<<<NN, 256, 0, stream>>>(mbuf, offsets, edge_dst, edge_w,
                                                 aggbuf);
        gemm_bf16s<1 | 2 | 4 | 16><<<g512, blk, 0, stream>>>(cur, V, aggbuf, nullptr,
                                                             nxt, bk + (size_t)i * CH,
                                                             NN, CH, CH);
        bf16* t = cur; cur = nxt; nxt = t;
    }

    // output: out = h @ Wd + bd
    gemm_bf16s<2 | 8><<<gout, blk, 0, stream>>>(cur, wdt, nullptr, out, nullptr,
                                                bd, NN, NL, CH);
}

// Round 3
// 971.459 us; speedup vs baseline: 1.8910x; 1.4852x over previous
//
#include <hip/hip_runtime.h>
#include <hip/hip_bf16.h>
#include <stdint.h>

#define NN 10000
#define NE 160000
#define INF 256
#define CH 512
#define NL 1440
#define MPAD 10112  // NN rounded up to 128

typedef __bf16 bf16;
typedef __attribute__((ext_vector_type(8))) bf16 bf16x8;
typedef __attribute__((ext_vector_type(4))) bf16 bf16x4;
typedef __attribute__((ext_vector_type(4))) float f32x4;

// Tiled operand layout: [panel(128 rows)][chunk(32 k')][g=4][row=128][j=8] bf16.
// chunk c covers k' in [c*32, c*32+32); hi plane chunks 0..KCh-1, lo plane KCh..2KCh-1.
// Within a chunk, element (row, g*8+j) sits at offset g*1024 + row*8 + j — exactly
// the unit order the GEMM stager consumes, so global_load_lds is lane-linear.

__device__ __forceinline__ void gload16(const void* g, const void* l) {
    auto gp = reinterpret_cast<const __attribute__((address_space(1))) uint32_t*>(
        reinterpret_cast<uintptr_t>(g));
    auto lp = reinterpret_cast<__attribute__((address_space(3))) uint32_t*>(
        reinterpret_cast<uintptr_t>(l));
    __builtin_amdgcn_global_load_lds(gp, lp, 16, 0, 0);
}

// ---------------- graph prep ----------------
__global__ void deg_kernel(const int* __restrict__ src, const int* __restrict__ dst,
                           int* __restrict__ deg_out, int* __restrict__ deg_in) {
    int e = blockIdx.x * 256 + threadIdx.x;
    if (e < NE) {
        atomicAdd(&deg_out[src[e]], 1);
        atomicAdd(&deg_in[dst[e]], 1);
    }
}

__global__ __launch_bounds__(1024) void scan_kernel(const int* __restrict__ deg,
                                                    int* __restrict__ offsets,
                                                    int* __restrict__ cursor) {
    __shared__ int sums[1024];
    const int PER = 10;
    int tid = threadIdx.x;
    int base = tid * PER;
    int local[PER];
    int s = 0;
    #pragma unroll
    for (int i = 0; i < PER; i++) {
        int v = (base + i < NN) ? deg[base + i] : 0;
        local[i] = s;
        s += v;
    }
    sums[tid] = s;
    __syncthreads();
    for (int off = 1; off < 1024; off <<= 1) {
        int v = (tid >= off) ? sums[tid - off] : 0;
        __syncthreads();
        sums[tid] += v;
        __syncthreads();
    }
    int prev = (tid > 0) ? sums[tid - 1] : 0;
    #pragma unroll
    for (int i = 0; i < PER; i++) {
        if (base + i < NN) {
            int o = prev + local[i];
            offsets[base + i] = o;
            cursor[base + i] = o;
        }
    }
    if (tid == 0) offsets[NN] = sums[1023];
}

__global__ void csr_kernel(const int* __restrict__ src, const int* __restrict__ dst,
                           const int* __restrict__ deg_out, const int* __restrict__ deg_in,
                           int* __restrict__ cursor, int* __restrict__ edge_dst,
                           float* __restrict__ edge_w) {
    int e = blockIdx.x * 256 + threadIdx.x;
    if (e < NE) {
        int s = src[e], d = dst[e];
        float dw = (float)max(deg_out[s], 1) * (float)max(deg_in[d], 1);
        float w = rsqrtf(dw);
        int pos = atomicAdd(&cursor[s], 1);
        edge_dst[pos] = d;
        edge_w[pos] = w;
    }
}

// ---------------- aggregation ----------------
__global__ __launch_bounds__(256) void aggregate_kernel(const float* __restrict__ m,
                                                        const int* __restrict__ offsets,
                                                        const int* __restrict__ edge_dst,
                                                        const float* __restrict__ edge_w,
                                                        float* __restrict__ out) {
    int u = blockIdx.x;
    int c = threadIdx.x;
    int beg = offsets[u], end = offsets[u + 1];
    float a0 = 0.f, a1 = 0.f;
    for (int e = beg; e < end; e++) {
        int d = edge_dst[e];
        float wt = edge_w[e];
        a0 += wt * m[(size_t)d * CH + c];
        a1 += wt * m[(size_t)d * CH + c + 256];
    }
    out[(size_t)u * CH + c] = a0;
    out[(size_t)u * CH + c + 256] = a1;
}

// ---------------- f32 [M][K] -> tiled split bf16 ----------------
__global__ void split_rows(const float* __restrict__ in, bf16* __restrict__ out,
                           int M, int K) {
    int idx = blockIdx.x * 256 + threadIdx.x;
    int K4 = K >> 2;
    if (idx >= M * K4) return;
    int m = idx / K4;
    int k4 = (idx % K4) * 4;
    int KCh = K >> 5;
    int KC2 = KCh * 2;
    float4 v = *(const float4*)&in[(size_t)m * K + k4];
    float vv[4] = {v.x, v.y, v.z, v.w};
    bf16x4 hi, lo;
    #pragma unroll
    for (int j = 0; j < 4; j++) {
        bf16 h = (bf16)vv[j];
        hi[j] = h;
        lo[j] = (bf16)(vv[j] - (float)h);
    }
    int panel = m >> 7, row = m & 127;
    int c = k4 >> 5, g = (k4 & 31) >> 3, j0 = k4 & 7;
    size_t base = ((size_t)panel * KC2) * 4096 + g * 1024 + row * 8 + j0;
    *(bf16x4*)&out[base + (size_t)c * 4096] = hi;
    *(bf16x4*)&out[base + (size_t)(KCh + c) * 4096] = lo;
}

// ---------------- W[K][N] f32 -> tiled split bf16 (B^T layout) ----------------
__global__ void tsplit(const float* __restrict__ in, bf16* __restrict__ out,
                       int K, int N, size_t inStride, size_t outStride) {
    int z = blockIdx.z;
    in += (size_t)z * inStride;
    out += (size_t)z * outStride;
    int idx = blockIdx.x * 256 + threadIdx.x;
    int K8 = K >> 3;
    if (idx >= N * K8) return;
    int k8 = (idx / N) * 8;
    int n = idx % N;
    int KCh = K >> 5;
    int KC2 = KCh * 2;
    bf16x8 hi, lo;
    #pragma unroll
    for (int j = 0; j < 8; j++) {
        float v = in[(size_t)(k8 + j) * N + n];
        bf16 h = (bf16)v;
        hi[j] = h;
        lo[j] = (bf16)(v - (float)h);
    }
    int panel = n >> 7, row = n & 127;
    int c = k8 >> 5, g = (k8 & 31) >> 3;
    size_t base = ((size_t)panel * KC2) * 4096 + g * 1024 + row * 8;
    *(bf16x8*)&out[base + (size_t)c * 4096] = hi;
    *(bf16x8*)&out[base + (size_t)(KCh + c) * 4096] = lo;
}

// ---------------- fused split-bf16 MFMA GEMM, double-buffered ----------------
// C = A@B in ~f32 via ah*bh + al*bh + ah*bl per k-chunk (48 MFMA / wave / chunk).
// FLAGS: 1 = add Cin, 2 = add bias, 4 = relu. Always writes f32 Fout.
template <int FLAGS>
__global__ __launch_bounds__(256) void gemm_fused(
    const bf16* __restrict__ At, const bf16* __restrict__ Bt,
    const float* __restrict__ Cin, float* __restrict__ Fout,
    const float* __restrict__ bias, int M, int N, int KCh) {
    // lds[buf][tile: 0=Ah 1=Al 2=Bh 3=Bl][4096]
    __shared__ bf16 lds[2][4][4096];

    int tid = threadIdx.x;
    int lane = tid & 63, w = tid >> 6;
    int wm = w >> 1, wn = w & 1;
    int lr = lane & 15, lg = lane >> 4;
    int by = blockIdx.y, bx = blockIdx.x;
    int KC2 = KCh * 2;

    const bf16* Abase = At + (size_t)by * KC2 * 4096;
    const bf16* Bbase = Bt + (size_t)bx * KC2 * 4096;

    f32x4 acc[4][4];
    #pragma unroll
    for (int i = 0; i < 4; i++)
        #pragma unroll
        for (int j = 0; j < 4; j++) {
            f32x4 z = {0.f, 0.f, 0.f, 0.f};
            acc[i][j] = z;
        }

    int u0 = tid, u1 = tid + 256;

    // fragment base offsets within a 4096-elem tile
    int offA = lg * 1024 + (wm * 64 + lr) * 8;
    int offB = lg * 1024 + (wn * 64 + lr) * 8;

    #define STAGE(bufi, t)                                                        \
        do {                                                                      \
            const bf16* sAh = Abase + (size_t)(t) * 4096;                         \
            const bf16* sAl = Abase + (size_t)(KCh + (t)) * 4096;                 \
            const bf16* sBh = Bbase + (size_t)(t) * 4096;                         \
            const bf16* sBl = Bbase + (size_t)(KCh + (t)) * 4096;                 \
            gload16(sAh + u0 * 8, &lds[bufi][0][u0 * 8]);                         \
            gload16(sAh + u1 * 8, &lds[bufi][0][u1 * 8]);                         \
            gload16(sAl + u0 * 8, &lds[bufi][1][u0 * 8]);                         \
            gload16(sAl + u1 * 8, &lds[bufi][1][u1 * 8]);                         \
            gload16(sBh + u0 * 8, &lds[bufi][2][u0 * 8]);                         \
            gload16(sBh + u1 * 8, &lds[bufi][2][u1 * 8]);                         \
            gload16(sBl + u0 * 8, &lds[bufi][3][u0 * 8]);                         \
            gload16(sBl + u1 * 8, &lds[bufi][3][u1 * 8]);                         \
        } while (0)

    STAGE(0, 0);
    __syncthreads();  // vmcnt(0) drain + barrier: buf0 ready

    int buf = 0;
    for (int t = 0; t < KCh; t++) {
        if (t + 1 < KCh) STAGE(buf ^ 1, t + 1);  // issue next-chunk loads early

        bf16x8 bh[4], bl[4];
        #pragma unroll
        for (int n = 0; n < 4; n++) {
            bh[n] = *(const bf16x8*)&lds[buf][2][offB + n * 128];
            bl[n] = *(const bf16x8*)&lds[buf][3][offB + n * 128];
        }
        #pragma unroll
        for (int m = 0; m < 4; m++) {
            bf16x8 ah = *(const bf16x8*)&lds[buf][0][offA + m * 128];
            bf16x8 al = *(const bf16x8*)&lds[buf][1][offA + m * 128];
            #pragma unroll
            for (int n = 0; n < 4; n++) {
                acc[m][n] = __builtin_amdgcn_mfma_f32_16x16x32_bf16(ah, bh[n],
                                                                   acc[m][n], 0, 0, 0);
                acc[m][n] = __builtin_amdgcn_mfma_f32_16x16x32_bf16(al, bh[n],
                                                                   acc[m][n], 0, 0, 0);
                acc[m][n] = __builtin_amdgcn_mfma_f32_16x16x32_bf16(ah, bl[n],
                                                                   acc[m][n], 0, 0, 0);
            }
        }
        __syncthreads();  // drains vmcnt (next buf staged) + all waves done reading buf
        buf ^= 1;
    }
    #undef STAGE

    // epilogue: C/D layout col = lane&15, row = (lane>>4)*4 + reg
    int m0 = by * 128, n0 = bx * 128;
    #pragma unroll
    for (int m = 0; m < 4; m++) {
        #pragma unroll
        for (int n = 0; n < 4; n++) {
            int grow0 = m0 + wm * 64 + m * 16 + lg * 4;
            int gcol = n0 + wn * 64 + n * 16 + lr;
            if (gcol >= N) continue;
            float bv = (FLAGS & 2) ? bias[gcol] : 0.f;
            #pragma unroll
            for (int r = 0; r < 4; r++) {
                int grow = grow0 + r;
                if (grow >= M) continue;
                float v = acc[m][n][r];
                if (FLAGS & 1) v += Cin[(size_t)grow * N + gcol];
                if (FLAGS & 2) v += bv;
                if (FLAGS & 4) v = fmaxf(v, 0.f);
                Fout[(size_t)grow * N + gcol] = v;
            }
        }
    }
}

// ---------------- host launch ----------------
extern "C" void kernel_launch(void* const* d_in, const int* in_sizes, int n_in,
                              void* d_out, int out_size, void* d_ws, size_t ws_size,
                              hipStream_t stream) {
    const float* x  = (const float*)d_in[0];
    const int* src  = (const int*)d_in[1];
    const int* dst  = (const int*)d_in[2];
    const float* W1 = (const float*)d_in[3];
    const float* V1 = (const float*)d_in[4];
    const float* b1 = (const float*)d_in[5];
    const float* Wk = (const float*)d_in[6];
    const float* Vk = (const float*)d_in[7];
    const float* bk = (const float*)d_in[8];
    const float* Wd = (const float*)d_in[9];
    const float* bd = (const float*)d_in[10];

    // ws layout (sizes identical to round 2's proven-fitting layout)
    int* deg_out  = (int*)d_ws;
    int* deg_in   = deg_out + 10240;
    int* offsets  = deg_in + 10240;
    int* cursor   = offsets + 10240;
    int* edge_dst = cursor + 10240;
    float* edge_w = (float*)(edge_dst + NE);
    bf16* bufA    = (bf16*)(edge_w + NE);            // 79 panels x 32 chunks x 4096
    bf16* bufB    = bufA + (size_t)79 * 32 * 4096;
    bf16* w1t     = bufB + (size_t)79 * 32 * 4096;   // 4 x 16 x 4096
    bf16* v1t     = w1t + (size_t)4 * 16 * 4096;
    bf16* wkt     = v1t + (size_t)4 * 16 * 4096;     // 6 x (4 x 32 x 4096)
    bf16* vkt     = wkt + (size_t)6 * 4 * 32 * 4096;
    bf16* wdt     = vkt + (size_t)6 * 4 * 32 * 4096; // 12 x 32 x 4096

    float* mbuf   = (float*)d_out;                   // [NN][CH] f32 scratch
    float* aggbuf = mbuf + (size_t)NN * CH;          // [NN][CH]
    float* out    = (float*)d_out;

    hipMemsetAsync(deg_out, 0, 2 * 10240 * sizeof(int), stream);
    deg_kernel<<<(NE + 255) / 256, 256, 0, stream>>>(src, dst, deg_out, deg_in);
    scan_kernel<<<1, 1024, 0, stream>>>(deg_out, offsets, cursor);
    csr_kernel<<<(NE + 255) / 256, 256, 0, stream>>>(src, dst, deg_out, deg_in,
                                                     cursor, edge_dst, edge_w);

    // one-time conversions into tiled split layout
    split_rows<<<(NN * (INF / 4) + 255) / 256, 256, 0, stream>>>(x, bufA, NN, INF);
    tsplit<<<dim3((512 * (INF / 8) + 255) / 256, 1, 1), 256, 0, stream>>>(
        W1, w1t, INF, 512, 0, 0);
    tsplit<<<dim3((512 * (INF / 8) + 255) / 256, 1, 1), 256, 0, stream>>>(
        V1, v1t, INF, 512, 0, 0);
    tsplit<<<dim3((512 * (CH / 8) + 255) / 256, 1, 6), 256, 0, stream>>>(
        Wk, wkt, CH, 512, (size_t)CH * 512, (size_t)4 * 32 * 4096);
    tsplit<<<dim3((512 * (CH / 8) + 255) / 256, 1, 6), 256, 0, stream>>>(
        Vk, vkt, CH, 512, (size_t)CH * 512, (size_t)4 * 32 * 4096);
    tsplit<<<dim3((NL * (CH / 8) + 255) / 256, 1, 1), 256, 0, stream>>>(
        Wd, wdt, CH, NL, 0, 0);

    dim3 blk(256);
    dim3 g512(4, 79);
    dim3 gout(12, 79);

    // layer 1 (K = 256, KCh = 8)
    gemm_fused<0><<<g512, blk, 0, stream>>>(bufA, w1t, nullptr, mbuf, nullptr,
                                            NN, CH, 8);
    aggregate_kernel<<<NN, 256, 0, stream>>>(mbuf, offsets, edge_dst, edge_w, aggbuf);
    gemm_fused<1 | 2 | 4><<<g512, blk, 0, stream>>>(bufA, v1t, aggbuf, mbuf, b1,
                                                    NN, CH, 8);
    split_rows<<<(NN * (CH / 4) + 255) / 256, 256, 0, stream>>>(mbuf, bufB, NN, CH);

    bf16* cur = bufB;
    bf16* nxt = bufA;
    for (int i = 0; i < 6; i++) {
        const bf16* W = wkt + (size_t)i * 4 * 32 * 4096;
        const bf16* V = vkt + (size_t)i * 4 * 32 * 4096;
        gemm_fused<0><<<g512, blk, 0, stream>>>(cur, W, nullptr, mbuf, nullptr,
                                                NN, CH, 16);
        aggregate_kernel<<<NN, 256, 0, stream>>>(mbuf, offsets, edge_dst, edge_w,
                                                 aggbuf);
        gemm_fused<1 | 2 | 4><<<g512, blk, 0, stream>>>(cur, V, aggbuf, mbuf,
                                                        bk + (size_t)i * CH, NN, CH, 16);
        split_rows<<<(NN * (CH / 4) + 255) / 256, 256, 0, stream>>>(mbuf, nxt, NN, CH);
        bf16* t = cur; cur = nxt; nxt = t;
    }

    // output: out = h @ Wd + bd  (K = 512, N = 1440)
    gemm_fused<2><<<gout, blk, 0, stream>>>(cur, wdt, nullptr, out, bd, NN, NL, 16);
}

// Round 4
// 853.446 us; speedup vs baseline: 2.1524x; 1.1383x over previous
//
#include <hip/hip_runtime.h>
#include <hip/hip_bf16.h>
#include <stdint.h>

#define NN 10000
#define NE 160000
#define INF 256
#define CH 512
#define NL 1440
#define MPAN 158   // ceil(10000/64) A panels

typedef __bf16 bf16;
typedef __attribute__((ext_vector_type(8))) bf16 bf16x8;
typedef __attribute__((ext_vector_type(4))) bf16 bf16x4;
typedef __attribute__((ext_vector_type(4))) float f32x4;

// A tiled layout: [panel(64 rows)][chunk(32 k')][g=4][row=64][j=8]   (2048 elem/chunk/plane)
// B tiled layout: [panel(128 cols)][chunk(32 k')][g=4][row=128][j=8] (4096 elem/chunk/plane)
// hi-plane chunks 0..KCh-1, lo-plane chunks KCh..2KCh-1. Unit order == stager lane order.

__device__ __forceinline__ void gload16(const void* g, const void* l) {
    auto gp = reinterpret_cast<const __attribute__((address_space(1))) uint32_t*>(
        reinterpret_cast<uintptr_t>(g));
    auto lp = reinterpret_cast<__attribute__((address_space(3))) uint32_t*>(
        reinterpret_cast<uintptr_t>(l));
    __builtin_amdgcn_global_load_lds(gp, lp, 16, 0, 0);
}

// ---------------- graph prep ----------------
__global__ void deg_kernel(const int* __restrict__ src, const int* __restrict__ dst,
                           int* __restrict__ deg_out, int* __restrict__ deg_in) {
    int e = blockIdx.x * 256 + threadIdx.x;
    if (e < NE) {
        atomicAdd(&deg_out[src[e]], 1);
        atomicAdd(&deg_in[dst[e]], 1);
    }
}

__global__ __launch_bounds__(1024) void scan_kernel(const int* __restrict__ deg,
                                                    int* __restrict__ offsets,
                                                    int* __restrict__ cursor) {
    __shared__ int sums[1024];
    const int PER = 10;
    int tid = threadIdx.x;
    int base = tid * PER;
    int local[PER];
    int s = 0;
    #pragma unroll
    for (int i = 0; i < PER; i++) {
        int v = (base + i < NN) ? deg[base + i] : 0;
        local[i] = s;
        s += v;
    }
    sums[tid] = s;
    __syncthreads();
    for (int off = 1; off < 1024; off <<= 1) {
        int v = (tid >= off) ? sums[tid - off] : 0;
        __syncthreads();
        sums[tid] += v;
        __syncthreads();
    }
    int prev = (tid > 0) ? sums[tid - 1] : 0;
    #pragma unroll
    for (int i = 0; i < PER; i++) {
        if (base + i < NN) {
            int o = prev + local[i];
            offsets[base + i] = o;
            cursor[base + i] = o;
        }
    }
    if (tid == 0) offsets[NN] = sums[1023];
}

__global__ void csr_kernel(const int* __restrict__ src, const int* __restrict__ dst,
                           const int* __restrict__ deg_out, const int* __restrict__ deg_in,
                           int* __restrict__ cursor, int* __restrict__ edge_dst,
                           float* __restrict__ edge_w) {
    int e = blockIdx.x * 256 + threadIdx.x;
    if (e < NE) {
        int s = src[e], d = dst[e];
        float dw = (float)max(deg_out[s], 1) * (float)max(deg_in[d], 1);
        float w = rsqrtf(dw);
        int pos = atomicAdd(&cursor[s], 1);
        edge_dst[pos] = d;
        edge_w[pos] = w;
    }
}

// ---------------- aggregation ----------------
__global__ __launch_bounds__(256) void aggregate_kernel(const float* __restrict__ m,
                                                        const int* __restrict__ offsets,
                                                        const int* __restrict__ edge_dst,
                                                        const float* __restrict__ edge_w,
                                                        float* __restrict__ out) {
    int u = blockIdx.x;
    int c = threadIdx.x;
    int beg = offsets[u], end = offsets[u + 1];
    float a0 = 0.f, a1 = 0.f;
    for (int e = beg; e < end; e++) {
        int d = edge_dst[e];
        float wt = edge_w[e];
        a0 += wt * m[(size_t)d * CH + c];
        a1 += wt * m[(size_t)d * CH + c + 256];
    }
    out[(size_t)u * CH + c] = a0;
    out[(size_t)u * CH + c + 256] = a1;
}

// ---------------- f32 [M][K] -> tiled split bf16 (A layout, 64-row panels) ----------------
__global__ void split_rows(const float* __restrict__ in, bf16* __restrict__ out,
                           int M, int K) {
    int idx = blockIdx.x * 256 + threadIdx.x;
    int K4 = K >> 2;
    if (idx >= M * K4) return;
    int m = idx / K4;
    int k4 = (idx % K4) * 4;
    int KCh = K >> 5;
    int KC2 = KCh * 2;
    float4 v = *(const float4*)&in[(size_t)m * K + k4];
    float vv[4] = {v.x, v.y, v.z, v.w};
    bf16x4 hi, lo;
    #pragma unroll
    for (int j = 0; j < 4; j++) {
        bf16 h = (bf16)vv[j];
        hi[j] = h;
        lo[j] = (bf16)(vv[j] - (float)h);
    }
    int panel = m >> 6, row = m & 63;
    int c = k4 >> 5, g = (k4 & 31) >> 3, j0 = k4 & 7;
    size_t base = ((size_t)panel * KC2) * 2048 + g * 512 + row * 8 + j0;
    *(bf16x4*)&out[base + (size_t)c * 2048] = hi;
    *(bf16x4*)&out[base + (size_t)(KCh + c) * 2048] = lo;
}

// ---------------- W[K][N] f32 -> tiled split bf16 (B^T layout, 128-col panels) --------
__global__ void tsplit(const float* __restrict__ in, bf16* __restrict__ out,
                       int K, int N, size_t inStride, size_t outStride) {
    int z = blockIdx.z;
    in += (size_t)z * inStride;
    out += (size_t)z * outStride;
    int idx = blockIdx.x * 256 + threadIdx.x;
    int K8 = K >> 3;
    if (idx >= N * K8) return;
    int k8 = (idx / N) * 8;
    int n = idx % N;
    int KCh = K >> 5;
    int KC2 = KCh * 2;
    bf16x8 hi, lo;
    #pragma unroll
    for (int j = 0; j < 8; j++) {
        float v = in[(size_t)(k8 + j) * N + n];
        bf16 h = (bf16)v;
        hi[j] = h;
        lo[j] = (bf16)(v - (float)h);
    }
    int panel = n >> 7, row = n & 127;
    int c = k8 >> 5, g = (k8 & 31) >> 3;
    size_t base = ((size_t)panel * KC2) * 4096 + g * 1024 + row * 8;
    *(bf16x8*)&out[base + (size_t)c * 4096] = hi;
    *(bf16x8*)&out[base + (size_t)(KCh + c) * 4096] = lo;
}

// ---------------- fused split-bf16 MFMA GEMM, 64x128 tile, XCD-swizzled ----------------
// FLAGS: 1 = add Cin, 2 = add bias, 4 = relu. Always writes f32 Fout.
template <int FLAGS>
__global__ __launch_bounds__(256, 3) void gemm_fused(
    const bf16* __restrict__ At, const bf16* __restrict__ Bt,
    const float* __restrict__ Cin, float* __restrict__ Fout,
    const float* __restrict__ bias, int M, int N, int KCh, int BX) {
    __shared__ bf16 ldsA[2][2][2048];  // [buf][hi/lo][64 rows x 32 k']
    __shared__ bf16 ldsB[2][2][4096];  // [buf][hi/lo][128 cols x 32 k']

    // bijective XCD swizzle (m204): tiles sharing an A panel colocate per XCD
    int nwg = gridDim.x;
    int q = nwg >> 3, r = nwg & 7;
    int p = blockIdx.x;
    int xcd = p & 7, slot = p >> 3;
    int L = (xcd < r ? xcd * (q + 1) : r * (q + 1) + (xcd - r) * q) + slot;
    int by = L / BX, bx = L % BX;

    int tid = threadIdx.x;
    int lane = tid & 63, w = tid >> 6;
    int wm = w >> 1, wn = w & 1;
    int lr = lane & 15, lg = lane >> 4;
    int KC2 = KCh * 2;

    const bf16* Abase = At + (size_t)by * KC2 * 2048;
    const bf16* Bbase = Bt + (size_t)bx * KC2 * 4096;

    f32x4 acc[2][4];
    #pragma unroll
    for (int i = 0; i < 2; i++)
        #pragma unroll
        for (int j = 0; j < 4; j++) {
            f32x4 z = {0.f, 0.f, 0.f, 0.f};
            acc[i][j] = z;
        }

    int u0 = tid, u1 = tid + 256;  // B stage units; A uses 1 unit/thread

    int offA = lg * 512 + (wm * 32 + lr) * 8;    // + m*128
    int offB = lg * 1024 + (wn * 64 + lr) * 8;   // + n*128

    #define STAGE(bufi, t)                                                        \
        do {                                                                      \
            const bf16* sAh = Abase + (size_t)(t) * 2048;                         \
            const bf16* sAl = Abase + (size_t)(KCh + (t)) * 2048;                 \
            const bf16* sBh = Bbase + (size_t)(t) * 4096;                         \
            const bf16* sBl = Bbase + (size_t)(KCh + (t)) * 4096;                 \
            gload16(sAh + tid * 8, &ldsA[bufi][0][tid * 8]);                      \
            gload16(sAl + tid * 8, &ldsA[bufi][1][tid * 8]);                      \
            gload16(sBh + u0 * 8, &ldsB[bufi][0][u0 * 8]);                        \
            gload16(sBh + u1 * 8, &ldsB[bufi][0][u1 * 8]);                        \
            gload16(sBl + u0 * 8, &ldsB[bufi][1][u0 * 8]);                        \
            gload16(sBl + u1 * 8, &ldsB[bufi][1][u1 * 8]);                        \
        } while (0)

    STAGE(0, 0);
    __syncthreads();

    int buf = 0;
    for (int t = 0; t < KCh; t++) {
        if (t + 1 < KCh) STAGE(buf ^ 1, t + 1);

        bf16x8 bh[4], bl[4];
        #pragma unroll
        for (int n = 0; n < 4; n++) {
            bh[n] = *(const bf16x8*)&ldsB[buf][0][offB + n * 128];
            bl[n] = *(const bf16x8*)&ldsB[buf][1][offB + n * 128];
        }
        #pragma unroll
        for (int m = 0; m < 2; m++) {
            bf16x8 ah = *(const bf16x8*)&ldsA[buf][0][offA + m * 128];
            bf16x8 al = *(const bf16x8*)&ldsA[buf][1][offA + m * 128];
            #pragma unroll
            for (int n = 0; n < 4; n++) {
                acc[m][n] = __builtin_amdgcn_mfma_f32_16x16x32_bf16(ah, bh[n],
                                                                   acc[m][n], 0, 0, 0);
                acc[m][n] = __builtin_amdgcn_mfma_f32_16x16x32_bf16(al, bh[n],
                                                                   acc[m][n], 0, 0, 0);
                acc[m][n] = __builtin_amdgcn_mfma_f32_16x16x32_bf16(ah, bl[n],
                                                                   acc[m][n], 0, 0, 0);
            }
        }
        __syncthreads();
        buf ^= 1;
    }
    #undef STAGE

    // epilogue: C/D layout col = lane&15, row = (lane>>4)*4 + reg
    int m0 = by * 64, n0 = bx * 128;
    #pragma unroll
    for (int m = 0; m < 2; m++) {
        #pragma unroll
        for (int n = 0; n < 4; n++) {
            int grow0 = m0 + wm * 32 + m * 16 + lg * 4;
            int gcol = n0 + wn * 64 + n * 16 + lr;
            if (gcol >= N) continue;
            float bv = (FLAGS & 2) ? bias[gcol] : 0.f;
            #pragma unroll
            for (int r2 = 0; r2 < 4; r2++) {
                int grow = grow0 + r2;
                if (grow >= M) continue;
                float v = acc[m][n][r2];
                if (FLAGS & 1) v += Cin[(size_t)grow * N + gcol];
                if (FLAGS & 2) v += bv;
                if (FLAGS & 4) v = fmaxf(v, 0.f);
                Fout[(size_t)grow * N + gcol] = v;
            }
        }
    }
}

// ---------------- host launch ----------------
extern "C" void kernel_launch(void* const* d_in, const int* in_sizes, int n_in,
                              void* d_out, int out_size, void* d_ws, size_t ws_size,
                              hipStream_t stream) {
    const float* x  = (const float*)d_in[0];
    const int* src  = (const int*)d_in[1];
    const int* dst  = (const int*)d_in[2];
    const float* W1 = (const float*)d_in[3];
    const float* V1 = (const float*)d_in[4];
    const float* b1 = (const float*)d_in[5];
    const float* Wk = (const float*)d_in[6];
    const float* Vk = (const float*)d_in[7];
    const float* bk = (const float*)d_in[8];
    const float* Wd = (const float*)d_in[9];
    const float* bd = (const float*)d_in[10];

    // ws layout (same total footprint as round 3, proven to fit)
    int* deg_out  = (int*)d_ws;
    int* deg_in   = deg_out + 10240;
    int* offsets  = deg_in + 10240;
    int* cursor   = offsets + 10240;
    int* edge_dst = cursor + 10240;
    float* edge_w = (float*)(edge_dst + NE);
    bf16* bufA    = (bf16*)(edge_w + NE);               // 158 panels x 32 chunks x 2048
    bf16* bufB    = bufA + (size_t)MPAN * 32 * 2048;
    bf16* w1t     = bufB + (size_t)MPAN * 32 * 2048;    // 4 x 16 x 4096
    bf16* v1t     = w1t + (size_t)4 * 16 * 4096;
    bf16* wkt     = v1t + (size_t)4 * 16 * 4096;        // 6 x (4 x 32 x 4096)
    bf16* vkt     = wkt + (size_t)6 * 4 * 32 * 4096;
    bf16* wdt     = vkt + (size_t)6 * 4 * 32 * 4096;    // 12 x 32 x 4096

    float* mbuf   = (float*)d_out;                      // [NN][CH] f32 scratch
    float* aggbuf = mbuf + (size_t)NN * CH;             // [NN][CH]
    float* out    = (float*)d_out;

    hipMemsetAsync(deg_out, 0, 2 * 10240 * sizeof(int), stream);
    deg_kernel<<<(NE + 255) / 256, 256, 0, stream>>>(src, dst, deg_out, deg_in);
    scan_kernel<<<1, 1024, 0, stream>>>(deg_out, offsets, cursor);
    csr_kernel<<<(NE + 255) / 256, 256, 0, stream>>>(src, dst, deg_out, deg_in,
                                                     cursor, edge_dst, edge_w);

    // one-time conversions into tiled split layout
    split_rows<<<(NN * (INF / 4) + 255) / 256, 256, 0, stream>>>(x, bufA, NN, INF);
    tsplit<<<dim3((512 * (INF / 8) + 255) / 256, 1, 1), 256, 0, stream>>>(
        W1, w1t, INF, 512, 0, 0);
    tsplit<<<dim3((512 * (INF / 8) + 255) / 256, 1, 1), 256, 0, stream>>>(
        V1, v1t, INF, 512, 0, 0);
    tsplit<<<dim3((512 * (CH / 8) + 255) / 256, 1, 6), 256, 0, stream>>>(
        Wk, wkt, CH, 512, (size_t)CH * 512, (size_t)4 * 32 * 4096);
    tsplit<<<dim3((512 * (CH / 8) + 255) / 256, 1, 6), 256, 0, stream>>>(
        Vk, vkt, CH, 512, (size_t)CH * 512, (size_t)4 * 32 * 4096);
    tsplit<<<dim3((NL * (CH / 8) + 255) / 256, 1, 1), 256, 0, stream>>>(
        Wd, wdt, CH, NL, 0, 0);

    dim3 blk(256);
    int g512 = MPAN * 4;    // 632 blocks (N=512: 4 bx tiles)
    int gout = MPAN * 12;   // 1896 blocks (N=1440: 12 bx tiles)

    // layer 1 (K = 256, KCh = 8)
    gemm_fused<0><<<g512, blk, 0, stream>>>(bufA, w1t, nullptr, mbuf, nullptr,
                                            NN, CH, 8, 4);
    aggregate_kernel<<<NN, 256, 0, stream>>>(mbuf, offsets, edge_dst, edge_w, aggbuf);
    gemm_fused<1 | 2 | 4><<<g512, blk, 0, stream>>>(bufA, v1t, aggbuf, mbuf, b1,
                                                    NN, CH, 8, 4);
    split_rows<<<(NN * (CH / 4) + 255) / 256, 256, 0, stream>>>(mbuf, bufB, NN, CH);

    bf16* cur = bufB;
    bf16* nxt = bufA;
    for (int i = 0; i < 6; i++) {
        const bf16* W = wkt + (size_t)i * 4 * 32 * 4096;
        const bf16* V = vkt + (size_t)i * 4 * 32 * 4096;
        gemm_fused<0><<<g512, blk, 0, stream>>>(cur, W, nullptr, mbuf, nullptr,
                                                NN, CH, 16, 4);
        aggregate_kernel<<<NN, 256, 0, stream>>>(mbuf, offsets, edge_dst, edge_w,
                                                 aggbuf);
        gemm_fused<1 | 2 | 4><<<g512, blk, 0, stream>>>(cur, V, aggbuf, mbuf,
                                                        bk + (size_t)i * CH, NN, CH,
                                                        16, 4);
        split_rows<<<(NN * (CH / 4) + 255) / 256, 256, 0, stream>>>(mbuf, nxt, NN, CH);
        bf16* t = cur; cur = nxt; nxt = t;
    }

    // output: out = h @ Wd + bd  (K = 512, N = 1440)
    gemm_fused<2><<<gout, blk, 0, stream>>>(cur, wdt, nullptr, out, bd, NN, NL, 16, 12);
}

// Round 5
// 681.895 us; speedup vs baseline: 2.6940x; 1.2516x over previous
//
#include <hip/hip_runtime.h>
#include <hip/hip_bf16.h>
#include <stdint.h>

#define NN 10000
#define NE 160000
#define INF 256
#define CH 512
#define NL 1440
#define MPAN 158   // ceil(10000/64) A panels

typedef __bf16 bf16;
typedef __attribute__((ext_vector_type(8))) bf16 bf16x8;
typedef __attribute__((ext_vector_type(4))) bf16 bf16x4;
typedef __attribute__((ext_vector_type(4))) float f32x4;

// A tiled layout: [panel(64 rows)][chunk(32 k')][g=4][row=64][j=8]   (2048 elem/chunk/plane)
// B tiled layout: [panel(128 cols)][chunk(32 k')][g=4][row=128][j=8] (4096 elem/chunk/plane)
// hi-plane chunks 0..KCh-1, lo-plane chunks KCh..2KCh-1. Unit order == stager lane order.

__device__ __forceinline__ void gload16(const void* g, const void* l) {
    auto gp = reinterpret_cast<const __attribute__((address_space(1))) uint32_t*>(
        reinterpret_cast<uintptr_t>(g));
    auto lp = reinterpret_cast<__attribute__((address_space(3))) uint32_t*>(
        reinterpret_cast<uintptr_t>(l));
    __builtin_amdgcn_global_load_lds(gp, lp, 16, 0, 0);
}

// ---------------- graph prep ----------------
__global__ void deg_kernel(const int* __restrict__ src, const int* __restrict__ dst,
                           int* __restrict__ deg_out, int* __restrict__ deg_in) {
    int e = blockIdx.x * 256 + threadIdx.x;
    if (e < NE) {
        atomicAdd(&deg_out[src[e]], 1);
        atomicAdd(&deg_in[dst[e]], 1);
    }
}

__global__ __launch_bounds__(1024) void scan_kernel(const int* __restrict__ deg,
                                                    int* __restrict__ offsets,
                                                    int* __restrict__ cursor) {
    __shared__ int sums[1024];
    const int PER = 10;
    int tid = threadIdx.x;
    int base = tid * PER;
    int local[PER];
    int s = 0;
    #pragma unroll
    for (int i = 0; i < PER; i++) {
        int v = (base + i < NN) ? deg[base + i] : 0;
        local[i] = s;
        s += v;
    }
    sums[tid] = s;
    __syncthreads();
    for (int off = 1; off < 1024; off <<= 1) {
        int v = (tid >= off) ? sums[tid - off] : 0;
        __syncthreads();
        sums[tid] += v;
        __syncthreads();
    }
    int prev = (tid > 0) ? sums[tid - 1] : 0;
    #pragma unroll
    for (int i = 0; i < PER; i++) {
        if (base + i < NN) {
            int o = prev + local[i];
            offsets[base + i] = o;
            cursor[base + i] = o;
        }
    }
    if (tid == 0) offsets[NN] = sums[1023];
}

__global__ void csr_kernel(const int* __restrict__ src, const int* __restrict__ dst,
                           const int* __restrict__ deg_out, const int* __restrict__ deg_in,
                           int* __restrict__ cursor, int* __restrict__ edge_dst,
                           float* __restrict__ edge_w) {
    int e = blockIdx.x * 256 + threadIdx.x;
    if (e < NE) {
        int s = src[e], d = dst[e];
        float dw = (float)max(deg_out[s], 1) * (float)max(deg_in[d], 1);
        float w = rsqrtf(dw);
        int pos = atomicAdd(&cursor[s], 1);
        edge_dst[pos] = d;
        edge_w[pos] = w;
    }
}

// ---------------- fused aggregate + residual + relu + split-to-tiled ----------------
// agg[u,c] = sum_e w*m[dst,c];  h' = relu(agg + p[u,c] + b[c]); write tiled hi/lo.
__global__ __launch_bounds__(256) void agg_fuse(
    const bf16* __restrict__ mb,     // [NN][512] bf16
    const float* __restrict__ pb,    // [NN][512] f32
    const float* __restrict__ bias,  // [512]
    const int* __restrict__ offsets,
    const int* __restrict__ edge_dst,
    const float* __restrict__ edge_w,
    bf16* __restrict__ outT) {       // A-tiled split, KCh_out = 16 (32 chunks)
    __shared__ bf16 sh[1024];  // [hi 512 | lo 512] by channel
    int u = blockIdx.x;
    int c = threadIdx.x;
    int beg = offsets[u], end = offsets[u + 1];
    float a0 = 0.f, a1 = 0.f;
    for (int e = beg; e < end; e++) {
        int d = edge_dst[e];
        float wt = edge_w[e];
        a0 += wt * (float)mb[d * 512 + c];
        a1 += wt * (float)mb[d * 512 + c + 256];
    }
    float v0 = fmaxf(a0 + pb[(size_t)u * 512 + c] + bias[c], 0.f);
    float v1 = fmaxf(a1 + pb[(size_t)u * 512 + c + 256] + bias[c + 256], 0.f);
    bf16 h0 = (bf16)v0, h1 = (bf16)v1;
    sh[c] = h0;
    sh[512 + c] = (bf16)(v0 - (float)h0);
    sh[c + 256] = h1;
    sh[512 + c + 256] = (bf16)(v1 - (float)h1);
    __syncthreads();
    if (c < 128) {
        int plane = c >> 6;           // 0 = hi, 1 = lo
        int t = c & 63;
        int ch = t >> 2, g = t & 3;   // chunk 0..15, group 0..3
        int row = u & 63, panel = u >> 6;
        size_t base = (size_t)panel * 32 * 2048 +
                      (size_t)(plane * 16 + ch) * 2048 + g * 512 + row * 8;
        *(bf16x8*)&outT[base] = *(const bf16x8*)&sh[plane * 512 + ch * 32 + g * 8];
    }
}

// ---------------- f32 [M][K] -> tiled split bf16 (A layout, 64-row panels) ------------
__global__ void split_rows(const float* __restrict__ in, bf16* __restrict__ out,
                           int M, int K) {
    int idx = blockIdx.x * 256 + threadIdx.x;
    int K4 = K >> 2;
    if (idx >= M * K4) return;
    int m = idx / K4;
    int k4 = (idx % K4) * 4;
    int KCh = K >> 5;
    int KC2 = KCh * 2;
    float4 v = *(const float4*)&in[(size_t)m * K + k4];
    float vv[4] = {v.x, v.y, v.z, v.w};
    bf16x4 hi, lo;
    #pragma unroll
    for (int j = 0; j < 4; j++) {
        bf16 h = (bf16)vv[j];
        hi[j] = h;
        lo[j] = (bf16)(vv[j] - (float)h);
    }
    int panel = m >> 6, row = m & 63;
    int c = k4 >> 5, g = (k4 & 31) >> 3, j0 = k4 & 7;
    size_t base = ((size_t)panel * KC2) * 2048 + g * 512 + row * 8 + j0;
    *(bf16x4*)&out[base + (size_t)c * 2048] = hi;
    *(bf16x4*)&out[base + (size_t)(KCh + c) * 2048] = lo;
}

// ---------------- W[K][N] f32 -> tiled split bf16 (B^T layout, 128-col panels) --------
__global__ void tsplit(const float* __restrict__ in, bf16* __restrict__ out,
                       int K, int N, size_t inStride, size_t outStride) {
    int z = blockIdx.z;
    in += (size_t)z * inStride;
    out += (size_t)z * outStride;
    int idx = blockIdx.x * 256 + threadIdx.x;
    int K8 = K >> 3;
    if (idx >= N * K8) return;
    int k8 = (idx / N) * 8;
    int n = idx % N;
    int KCh = K >> 5;
    int KC2 = KCh * 2;
    bf16x8 hi, lo;
    #pragma unroll
    for (int j = 0; j < 8; j++) {
        float v = in[(size_t)(k8 + j) * N + n];
        bf16 h = (bf16)v;
        hi[j] = h;
        lo[j] = (bf16)(v - (float)h);
    }
    int panel = n >> 7, row = n & 127;
    int c = k8 >> 5, g = (k8 & 31) >> 3;
    size_t base = ((size_t)panel * KC2) * 4096 + g * 1024 + row * 8;
    *(bf16x8*)&out[base + (size_t)c * 4096] = hi;
    *(bf16x8*)&out[base + (size_t)(KCh + c) * 4096] = lo;
}

// ---------------- shared GEMM core macros ----------------
#define GEMM_PROLOGUE()                                                           \
    int nwg = gridDim.x;                                                          \
    int q = nwg >> 3, r = nwg & 7;                                                \
    int p = blockIdx.x;                                                           \
    int xcd = p & 7, slot = p >> 3;                                               \
    int L = (xcd < r ? xcd * (q + 1) : r * (q + 1) + (xcd - r) * q) + slot;       \
    int by = L / BX, bx = L % BX;                                                 \
    int tid = threadIdx.x;                                                        \
    int lane = tid & 63, w = tid >> 6;                                            \
    int wm = w >> 1, wn = w & 1;                                                  \
    int lr = lane & 15, lg = lane >> 4;                                           \
    int KC2 = KCh * 2;                                                            \
    const bf16* Abase = At + (size_t)by * KC2 * 2048;                             \
    const bf16* Bbase = Bt + (size_t)bx * KC2 * 4096;                             \
    f32x4 acc[2][4];                                                              \
    _Pragma("unroll") for (int i = 0; i < 2; i++)                                 \
        _Pragma("unroll") for (int j = 0; j < 4; j++) {                           \
            f32x4 z = {0.f, 0.f, 0.f, 0.f};                                       \
            acc[i][j] = z;                                                        \
        }                                                                         \
    int u0 = tid, u1 = tid + 256;                                                 \
    int offA = lg * 512 + (wm * 32 + lr) * 8;                                     \
    int offB = lg * 1024 + (wn * 64 + lr) * 8;

#define STAGE(bufi, t)                                                            \
    do {                                                                          \
        const bf16* sAh = Abase + (size_t)(t) * 2048;                             \
        const bf16* sAl = Abase + (size_t)(KCh + (t)) * 2048;                     \
        const bf16* sBh = Bbase + (size_t)(t) * 4096;                             \
        const bf16* sBl = Bbase + (size_t)(KCh + (t)) * 4096;                     \
        gload16(sAh + tid * 8, &ldsA[bufi][0][tid * 8]);                          \
        gload16(sAl + tid * 8, &ldsA[bufi][1][tid * 8]);                          \
        gload16(sBh + u0 * 8, &ldsB[bufi][0][u0 * 8]);                            \
        gload16(sBh + u1 * 8, &ldsB[bufi][0][u1 * 8]);                            \
        gload16(sBl + u0 * 8, &ldsB[bufi][1][u0 * 8]);                            \
        gload16(sBl + u1 * 8, &ldsB[bufi][1][u1 * 8]);                            \
    } while (0)

#define GEMM_MAINLOOP()                                                           \
    STAGE(0, 0);                                                                  \
    __syncthreads();                                                              \
    int buf = 0;                                                                  \
    for (int t = 0; t < KCh; t++) {                                               \
        if (t + 1 < KCh) STAGE(buf ^ 1, t + 1);                                   \
        bf16x8 bh[4], bl[4];                                                      \
        _Pragma("unroll") for (int n = 0; n < 4; n++) {                           \
            bh[n] = *(const bf16x8*)&ldsB[buf][0][offB + n * 128];                \
            bl[n] = *(const bf16x8*)&ldsB[buf][1][offB + n * 128];                \
        }                                                                         \
        _Pragma("unroll") for (int m = 0; m < 2; m++) {                           \
            bf16x8 ah = *(const bf16x8*)&ldsA[buf][0][offA + m * 128];            \
            bf16x8 al = *(const bf16x8*)&ldsA[buf][1][offA + m * 128];            \
            _Pragma("unroll") for (int n = 0; n < 4; n++) {                       \
                acc[m][n] = __builtin_amdgcn_mfma_f32_16x16x32_bf16(              \
                    ah, bh[n], acc[m][n], 0, 0, 0);                               \
                acc[m][n] = __builtin_amdgcn_mfma_f32_16x16x32_bf16(              \
                    al, bh[n], acc[m][n], 0, 0, 0);                               \
                acc[m][n] = __builtin_amdgcn_mfma_f32_16x16x32_bf16(              \
                    ah, bl[n], acc[m][n], 0, 0, 0);                               \
            }                                                                     \
        }                                                                         \
        __syncthreads();                                                          \
        buf ^= 1;                                                                 \
    }

// ---------------- WV-GEMM: A @ [W|V] -> m (bf16, cols 0..511) + p (f32, 512..1023) ----
__global__ __launch_bounds__(256, 3) void gemm_wv(
    const bf16* __restrict__ At, const bf16* __restrict__ Bt,
    bf16* __restrict__ mOut, float* __restrict__ pOut,
    int M, int KCh, int BX) {
    __shared__ bf16 ldsA[2][2][2048];
    __shared__ bf16 ldsB[2][2][4096];
    GEMM_PROLOGUE();
    GEMM_MAINLOOP();

    int m0 = by * 64, n0 = bx * 128;
    if (n0 < 512) {  // m plane: bf16
        #pragma unroll
        for (int m = 0; m < 2; m++)
            #pragma unroll
            for (int n = 0; n < 4; n++) {
                int grow0 = m0 + wm * 32 + m * 16 + lg * 4;
                int gcol = n0 + wn * 64 + n * 16 + lr;
                #pragma unroll
                for (int r2 = 0; r2 < 4; r2++) {
                    int grow = grow0 + r2;
                    if (grow < M) mOut[(size_t)grow * 512 + gcol] = (bf16)acc[m][n][r2];
                }
            }
    } else {  // p plane: f32
        #pragma unroll
        for (int m = 0; m < 2; m++)
            #pragma unroll
            for (int n = 0; n < 4; n++) {
                int grow0 = m0 + wm * 32 + m * 16 + lg * 4;
                int gcol = n0 - 512 + wn * 64 + n * 16 + lr;
                #pragma unroll
                for (int r2 = 0; r2 < 4; r2++) {
                    int grow = grow0 + r2;
                    if (grow < M) pOut[(size_t)grow * 512 + gcol] = acc[m][n][r2];
                }
            }
    }
}

// ---------------- final GEMM: A @ Wd + bd -> f32 out ----------------
__global__ __launch_bounds__(256, 3) void gemm_out(
    const bf16* __restrict__ At, const bf16* __restrict__ Bt,
    float* __restrict__ Fout, const float* __restrict__ bias,
    int M, int N, int KCh, int BX) {
    __shared__ bf16 ldsA[2][2][2048];
    __shared__ bf16 ldsB[2][2][4096];
    GEMM_PROLOGUE();
    GEMM_MAINLOOP();

    int m0 = by * 64, n0 = bx * 128;
    #pragma unroll
    for (int m = 0; m < 2; m++)
        #pragma unroll
        for (int n = 0; n < 4; n++) {
            int grow0 = m0 + wm * 32 + m * 16 + lg * 4;
            int gcol = n0 + wn * 64 + n * 16 + lr;
            if (gcol >= N) continue;
            float bv = bias[gcol];
            #pragma unroll
            for (int r2 = 0; r2 < 4; r2++) {
                int grow = grow0 + r2;
                if (grow < M) Fout[(size_t)grow * N + gcol] = acc[m][n][r2] + bv;
            }
        }
}

// ---------------- host launch ----------------
extern "C" void kernel_launch(void* const* d_in, const int* in_sizes, int n_in,
                              void* d_out, int out_size, void* d_ws, size_t ws_size,
                              hipStream_t stream) {
    const float* x  = (const float*)d_in[0];
    const int* src  = (const int*)d_in[1];
    const int* dst  = (const int*)d_in[2];
    const float* W1 = (const float*)d_in[3];
    const float* V1 = (const float*)d_in[4];
    const float* b1 = (const float*)d_in[5];
    const float* Wk = (const float*)d_in[6];
    const float* Vk = (const float*)d_in[7];
    const float* bk = (const float*)d_in[8];
    const float* Wd = (const float*)d_in[9];
    const float* bd = (const float*)d_in[10];

    // ws layout
    int* deg_out  = (int*)d_ws;
    int* deg_in   = deg_out + 10240;
    int* offsets  = deg_in + 10240;
    int* cursor   = offsets + 10240;
    int* edge_dst = cursor + 10240;
    float* edge_w = (float*)(edge_dst + NE);
    bf16* bufA    = (bf16*)(edge_w + NE);               // MPAN x 32 x 2048
    bf16* bufB    = bufA + (size_t)MPAN * 32 * 2048;
    bf16* w1v1t   = bufB + (size_t)MPAN * 32 * 2048;    // 8 panels x 16 x 4096
    bf16* wvkt    = w1v1t + (size_t)8 * 16 * 4096;      // 6 x 8 panels x 32 x 4096
    bf16* wdt     = wvkt + (size_t)6 * 8 * 32 * 4096;   // 12 panels x 32 x 4096

    // d_out doubles as m/p scratch (dead before final GEMM writes)
    float* pb = (float*)d_out;                          // [NN][512] f32
    bf16* mb  = (bf16*)(pb + (size_t)NN * 512);         // [NN][512] bf16
    float* out = (float*)d_out;

    hipMemsetAsync(deg_out, 0, 2 * 10240 * sizeof(int), stream);
    deg_kernel<<<(NE + 255) / 256, 256, 0, stream>>>(src, dst, deg_out, deg_in);
    scan_kernel<<<1, 1024, 0, stream>>>(deg_out, offsets, cursor);
    csr_kernel<<<(NE + 255) / 256, 256, 0, stream>>>(src, dst, deg_out, deg_in,
                                                     cursor, edge_dst, edge_w);

    // one-time conversions
    split_rows<<<(NN * (INF / 4) + 255) / 256, 256, 0, stream>>>(x, bufA, NN, INF);
    tsplit<<<dim3((512 * (INF / 8) + 255) / 256, 1, 1), 256, 0, stream>>>(
        W1, w1v1t, INF, 512, 0, 0);
    tsplit<<<dim3((512 * (INF / 8) + 255) / 256, 1, 1), 256, 0, stream>>>(
        V1, w1v1t + (size_t)4 * 16 * 4096, INF, 512, 0, 0);
    tsplit<<<dim3((512 * (CH / 8) + 255) / 256, 1, 6), 256, 0, stream>>>(
        Wk, wvkt, CH, 512, (size_t)CH * 512, (size_t)8 * 32 * 4096);
    tsplit<<<dim3((512 * (CH / 8) + 255) / 256, 1, 6), 256, 0, stream>>>(
        Vk, wvkt + (size_t)4 * 32 * 4096, CH, 512, (size_t)CH * 512,
        (size_t)8 * 32 * 4096);
    tsplit<<<dim3((NL * (CH / 8) + 255) / 256, 1, 1), 256, 0, stream>>>(
        Wd, wdt, CH, NL, 0, 0);

    dim3 blk(256);
    int gwv = MPAN * 8;     // 1264 blocks (N=1024: 8 bx tiles)
    int gout = MPAN * 12;   // 1896 blocks (N=1440: 12 bx tiles)

    // layer 1 (K = 256, KCh = 8)
    gemm_wv<<<gwv, blk, 0, stream>>>(bufA, w1v1t, mb, pb, NN, 8, 8);
    agg_fuse<<<NN, blk, 0, stream>>>(mb, pb, b1, offsets, edge_dst, edge_w, bufB);

    bf16* cur = bufB;
    bf16* nxt = bufA;
    for (int i = 0; i < 6; i++) {
        const bf16* WV = wvkt + (size_t)i * 8 * 32 * 4096;
        gemm_wv<<<gwv, blk, 0, stream>>>(cur, WV, mb, pb, NN, 16, 8);
        agg_fuse<<<NN, blk, 0, stream>>>(mb, pb, bk + (size_t)i * CH, offsets,
                                         edge_dst, edge_w, nxt);
        bf16* t = cur; cur = nxt; nxt = t;
    }

    // output: out = h @ Wd + bd  (K = 512, N = 1440)
    gemm_out<<<gout, blk, 0, stream>>>(cur, wdt, out, bd, NN, NL, 16, 12);
}

// Round 6
// 602.501 us; speedup vs baseline: 3.0490x; 1.1318x over previous
//
#include <hip/hip_runtime.h>
#include <hip/hip_bf16.h>
#include <stdint.h>

#define NN 10000
#define NE 160000
#define INF 256
#define CH 512
#define NL 1440
#define MPAN 158   // ceil(10000/64) A panels (64-row)

typedef __bf16 bf16;
typedef __attribute__((ext_vector_type(8))) bf16 bf16x8;
typedef __attribute__((ext_vector_type(4))) bf16 bf16x4;
typedef __attribute__((ext_vector_type(4))) float f32x4;

// A tiled layout: [panel(64 rows)][chunk(32 k')][g=4][row=64][j=8]   (2048 elem/chunk/plane)
// B tiled layout: [panel(128 cols)][chunk(32 k')][g=4][col=128][j=8] (4096 elem/chunk/plane)
// hi-plane chunks 0..KCh-1, lo-plane chunks KCh..2KCh-1. Unit order == stager lane order.
// GEMM is 2-pass split: C = ah*bh + al*bh  (A exact, B effectively bf16; B-lo never read).

__device__ __forceinline__ void gload16(const void* g, const void* l) {
    auto gp = reinterpret_cast<const __attribute__((address_space(1))) uint32_t*>(
        reinterpret_cast<uintptr_t>(g));
    auto lp = reinterpret_cast<__attribute__((address_space(3))) uint32_t*>(
        reinterpret_cast<uintptr_t>(l));
    __builtin_amdgcn_global_load_lds(gp, lp, 16, 0, 0);
}

// ---------------- graph prep ----------------
__global__ void deg_kernel(const int* __restrict__ src, const int* __restrict__ dst,
                           int* __restrict__ deg_out, int* __restrict__ deg_in) {
    int e = blockIdx.x * 256 + threadIdx.x;
    if (e < NE) {
        atomicAdd(&deg_out[src[e]], 1);
        atomicAdd(&deg_in[dst[e]], 1);
    }
}

__global__ __launch_bounds__(1024) void scan_kernel(const int* __restrict__ deg,
                                                    int* __restrict__ offsets,
                                                    int* __restrict__ cursor) {
    __shared__ int sums[1024];
    const int PER = 10;
    int tid = threadIdx.x;
    int base = tid * PER;
    int local[PER];
    int s = 0;
    #pragma unroll
    for (int i = 0; i < PER; i++) {
        int v = (base + i < NN) ? deg[base + i] : 0;
        local[i] = s;
        s += v;
    }
    sums[tid] = s;
    __syncthreads();
    for (int off = 1; off < 1024; off <<= 1) {
        int v = (tid >= off) ? sums[tid - off] : 0;
        __syncthreads();
        sums[tid] += v;
        __syncthreads();
    }
    int prev = (tid > 0) ? sums[tid - 1] : 0;
    #pragma unroll
    for (int i = 0; i < PER; i++) {
        if (base + i < NN) {
            int o = prev + local[i];
            offsets[base + i] = o;
            cursor[base + i] = o;
        }
    }
    if (tid == 0) offsets[NN] = sums[1023];
}

__global__ void csr_kernel(const int* __restrict__ src, const int* __restrict__ dst,
                           const int* __restrict__ deg_out, const int* __restrict__ deg_in,
                           int* __restrict__ cursor, int* __restrict__ edge_dst,
                           float* __restrict__ edge_w) {
    int e = blockIdx.x * 256 + threadIdx.x;
    if (e < NE) {
        int s = src[e], d = dst[e];
        float dw = (float)max(deg_out[s], 1) * (float)max(deg_in[d], 1);
        float w = rsqrtf(dw);
        int pos = atomicAdd(&cursor[s], 1);
        edge_dst[pos] = d;
        edge_w[pos] = w;
    }
}

// ---------------- fused aggregate + residual + relu + split-to-tiled ----------------
__global__ __launch_bounds__(256) void agg_fuse(
    const bf16* __restrict__ mb,     // [NN][512] bf16
    const float* __restrict__ pb,    // [NN][512] f32
    const float* __restrict__ bias,  // [512]
    const int* __restrict__ offsets,
    const int* __restrict__ edge_dst,
    const float* __restrict__ edge_w,
    bf16* __restrict__ outT) {       // A-tiled split, KCh_out = 16 (32 chunks)
    __shared__ bf16 sh[1024];  // [hi 512 | lo 512] by channel
    int u = blockIdx.x;
    int c = threadIdx.x;
    int beg = offsets[u], end = offsets[u + 1];
    float a0 = 0.f, a1 = 0.f;
    for (int e = beg; e < end; e++) {
        int d = edge_dst[e];
        float wt = edge_w[e];
        a0 += wt * (float)mb[d * 512 + c];
        a1 += wt * (float)mb[d * 512 + c + 256];
    }
    float v0 = fmaxf(a0 + pb[(size_t)u * 512 + c] + bias[c], 0.f);
    float v1 = fmaxf(a1 + pb[(size_t)u * 512 + c + 256] + bias[c + 256], 0.f);
    bf16 h0 = (bf16)v0, h1 = (bf16)v1;
    sh[c] = h0;
    sh[512 + c] = (bf16)(v0 - (float)h0);
    sh[c + 256] = h1;
    sh[512 + c + 256] = (bf16)(v1 - (float)h1);
    __syncthreads();
    if (c < 128) {
        int plane = c >> 6;           // 0 = hi, 1 = lo
        int t = c & 63;
        int ch = t >> 2, g = t & 3;   // chunk 0..15, group 0..3
        int row = u & 63, panel = u >> 6;
        size_t base = (size_t)panel * 32 * 2048 +
                      (size_t)(plane * 16 + ch) * 2048 + g * 512 + row * 8;
        *(bf16x8*)&outT[base] = *(const bf16x8*)&sh[plane * 512 + ch * 32 + g * 8];
    }
}

// ---------------- f32 [M][K] -> tiled split bf16 (A layout, 64-row panels) ------------
__global__ void split_rows(const float* __restrict__ in, bf16* __restrict__ out,
                           int M, int K) {
    int idx = blockIdx.x * 256 + threadIdx.x;
    int K4 = K >> 2;
    if (idx >= M * K4) return;
    int m = idx / K4;
    int k4 = (idx % K4) * 4;
    int KCh = K >> 5;
    int KC2 = KCh * 2;
    float4 v = *(const float4*)&in[(size_t)m * K + k4];
    float vv[4] = {v.x, v.y, v.z, v.w};
    bf16x4 hi, lo;
    #pragma unroll
    for (int j = 0; j < 4; j++) {
        bf16 h = (bf16)vv[j];
        hi[j] = h;
        lo[j] = (bf16)(vv[j] - (float)h);
    }
    int panel = m >> 6, row = m & 63;
    int c = k4 >> 5, g = (k4 & 31) >> 3, j0 = k4 & 7;
    size_t base = ((size_t)panel * KC2) * 2048 + g * 512 + row * 8 + j0;
    *(bf16x4*)&out[base + (size_t)c * 2048] = hi;
    *(bf16x4*)&out[base + (size_t)(KCh + c) * 2048] = lo;
}

// ---------------- W[K][N] f32 -> tiled bf16-hi (B^T layout, 128-col panels) -----------
__global__ void tsplit(const float* __restrict__ in, bf16* __restrict__ out,
                       int K, int N, size_t inStride, size_t outStride) {
    int z = blockIdx.z;
    in += (size_t)z * inStride;
    out += (size_t)z * outStride;
    int idx = blockIdx.x * 256 + threadIdx.x;
    int K8 = K >> 3;
    if (idx >= N * K8) return;
    int k8 = (idx / N) * 8;
    int n = idx % N;
    int KCh = K >> 5;
    bf16x8 hi;
    #pragma unroll
    for (int j = 0; j < 8; j++) hi[j] = (bf16)in[(size_t)(k8 + j) * N + n];
    int panel = n >> 7, row = n & 127;
    int c = k8 >> 5, g = (k8 & 31) >> 3;
    size_t base = ((size_t)panel * KCh) * 4096 + g * 1024 + row * 8;
    *(bf16x8*)&out[base + (size_t)c * 4096] = hi;
}

// ---------------- shared GEMM core (128x128 tile, 2-pass split) ----------------
#define GEMM_PROLOGUE()                                                           \
    int nwg = gridDim.x;                                                          \
    int q = nwg >> 3, r = nwg & 7;                                                \
    int p = blockIdx.x;                                                           \
    int xcd = p & 7, slot = p >> 3;                                               \
    int L = (xcd < r ? xcd * (q + 1) : r * (q + 1) + (xcd - r) * q) + slot;       \
    int by = L / BX, bx = L % BX;                                                 \
    int tid = threadIdx.x;                                                        \
    int lane = tid & 63, w = tid >> 6;                                            \
    int wm = w >> 1, wn = w & 1;                                                  \
    int lr = lane & 15, lg = lane >> 4;                                           \
    const bf16* Ab0 = At + (size_t)(2 * by) * (KCh * 2) * 2048;                   \
    const bf16* Ab1 = At + (size_t)(2 * by + 1) * (KCh * 2) * 2048;               \
    const bf16* Bbase = Bt + (size_t)bx * KCh * 4096;                             \
    f32x4 acc[4][4];                                                              \
    _Pragma("unroll") for (int i = 0; i < 4; i++)                                 \
        _Pragma("unroll") for (int j = 0; j < 4; j++) {                           \
            f32x4 z = {0.f, 0.f, 0.f, 0.f};                                       \
            acc[i][j] = z;                                                        \
        }                                                                         \
    int u0 = tid, u1 = tid + 256;                                                 \
    int offA = lg * 512 + lr * 8;                                                 \
    int offB = lg * 1024 + (wn * 64 + lr) * 8;

#define STAGE(bufi, t)                                                            \
    do {                                                                          \
        const bf16* s0h = Ab0 + (size_t)(t) * 2048;                               \
        const bf16* s1h = Ab1 + (size_t)(t) * 2048;                               \
        const bf16* s0l = Ab0 + (size_t)(KCh + (t)) * 2048;                       \
        const bf16* s1l = Ab1 + (size_t)(KCh + (t)) * 2048;                       \
        const bf16* sBh = Bbase + (size_t)(t) * 4096;                             \
        gload16(s0h + tid * 8, &ldsA[bufi][0][0][tid * 8]);                       \
        gload16(s1h + tid * 8, &ldsA[bufi][0][1][tid * 8]);                       \
        gload16(s0l + tid * 8, &ldsA[bufi][1][0][tid * 8]);                       \
        gload16(s1l + tid * 8, &ldsA[bufi][1][1][tid * 8]);                       \
        gload16(sBh + u0 * 8, &ldsB[bufi][u0 * 8]);                               \
        gload16(sBh + u1 * 8, &ldsB[bufi][u1 * 8]);                               \
    } while (0)

#define GEMM_MAINLOOP()                                                           \
    STAGE(0, 0);                                                                  \
    __syncthreads();                                                              \
    int buf = 0;                                                                  \
    for (int t = 0; t < KCh; t++) {                                               \
        if (t + 1 < KCh) STAGE(buf ^ 1, t + 1);                                   \
        bf16x8 bh[4];                                                             \
        _Pragma("unroll") for (int n = 0; n < 4; n++)                             \
            bh[n] = *(const bf16x8*)&ldsB[buf][offB + n * 128];                   \
        _Pragma("unroll") for (int m = 0; m < 4; m++) {                           \
            bf16x8 ah = *(const bf16x8*)&ldsA[buf][0][wm][offA + m * 128];        \
            bf16x8 al = *(const bf16x8*)&ldsA[buf][1][wm][offA + m * 128];        \
            _Pragma("unroll") for (int n = 0; n < 4; n++) {                       \
                acc[m][n] = __builtin_amdgcn_mfma_f32_16x16x32_bf16(              \
                    ah, bh[n], acc[m][n], 0, 0, 0);                               \
                acc[m][n] = __builtin_amdgcn_mfma_f32_16x16x32_bf16(              \
                    al, bh[n], acc[m][n], 0, 0, 0);                               \
            }                                                                     \
        }                                                                         \
        __syncthreads();                                                          \
        buf ^= 1;                                                                 \
    }

// ---------------- WV-GEMM: A @ [W|V] -> m (bf16, cols 0..511) + p (f32, 512..1023) ----
__global__ __launch_bounds__(256, 3) void gemm_wv(
    const bf16* __restrict__ At, const bf16* __restrict__ Bt,
    bf16* __restrict__ mOut, float* __restrict__ pOut,
    int M, int KCh, int BX) {
    __shared__ bf16 ldsA[2][2][2][2048];  // [buf][plane][panel-half][64r x 32k]
    __shared__ bf16 ldsB[2][4096];        // [buf][128c x 32k] hi only
    GEMM_PROLOGUE();
    GEMM_MAINLOOP();

    int m0 = by * 128, n0 = bx * 128;
    if (n0 < 512) {  // m plane: bf16
        #pragma unroll
        for (int m = 0; m < 4; m++)
            #pragma unroll
            for (int n = 0; n < 4; n++) {
                int grow0 = m0 + wm * 64 + m * 16 + lg * 4;
                int gcol = n0 + wn * 64 + n * 16 + lr;
                #pragma unroll
                for (int r2 = 0; r2 < 4; r2++) {
                    int grow = grow0 + r2;
                    if (grow < M) mOut[(size_t)grow * 512 + gcol] = (bf16)acc[m][n][r2];
                }
            }
    } else {  // p plane: f32
        #pragma unroll
        for (int m = 0; m < 4; m++)
            #pragma unroll
            for (int n = 0; n < 4; n++) {
                int grow0 = m0 + wm * 64 + m * 16 + lg * 4;
                int gcol = n0 - 512 + wn * 64 + n * 16 + lr;
                #pragma unroll
                for (int r2 = 0; r2 < 4; r2++) {
                    int grow = grow0 + r2;
                    if (grow < M) pOut[(size_t)grow * 512 + gcol] = acc[m][n][r2];
                }
            }
    }
}

// ---------------- final GEMM: A @ Wd + bd -> f32 out ----------------
__global__ __launch_bounds__(256, 3) void gemm_out(
    const bf16* __restrict__ At, const bf16* __restrict__ Bt,
    float* __restrict__ Fout, const float* __restrict__ bias,
    int M, int N, int KCh, int BX) {
    __shared__ bf16 ldsA[2][2][2][2048];
    __shared__ bf16 ldsB[2][4096];
    GEMM_PROLOGUE();
    GEMM_MAINLOOP();

    int m0 = by * 128, n0 = bx * 128;
    #pragma unroll
    for (int m = 0; m < 4; m++)
        #pragma unroll
        for (int n = 0; n < 4; n++) {
            int grow0 = m0 + wm * 64 + m * 16 + lg * 4;
            int gcol = n0 + wn * 64 + n * 16 + lr;
            if (gcol >= N) continue;
            float bv = bias[gcol];
            #pragma unroll
            for (int r2 = 0; r2 < 4; r2++) {
                int grow = grow0 + r2;
                if (grow < M) Fout[(size_t)grow * N + gcol] = acc[m][n][r2] + bv;
            }
        }
}

// ---------------- host launch ----------------
extern "C" void kernel_launch(void* const* d_in, const int* in_sizes, int n_in,
                              void* d_out, int out_size, void* d_ws, size_t ws_size,
                              hipStream_t stream) {
    const float* x  = (const float*)d_in[0];
    const int* src  = (const int*)d_in[1];
    const int* dst  = (const int*)d_in[2];
    const float* W1 = (const float*)d_in[3];
    const float* V1 = (const float*)d_in[4];
    const float* b1 = (const float*)d_in[5];
    const float* Wk = (const float*)d_in[6];
    const float* Vk = (const float*)d_in[7];
    const float* bk = (const float*)d_in[8];
    const float* Wd = (const float*)d_in[9];
    const float* bd = (const float*)d_in[10];

    // ws layout
    int* deg_out  = (int*)d_ws;
    int* deg_in   = deg_out + 10240;
    int* offsets  = deg_in + 10240;
    int* cursor   = offsets + 10240;
    int* edge_dst = cursor + 10240;
    float* edge_w = (float*)(edge_dst + NE);
    bf16* bufA    = (bf16*)(edge_w + NE);               // MPAN x 32 x 2048
    bf16* bufB    = bufA + (size_t)MPAN * 32 * 2048;
    bf16* w1v1t   = bufB + (size_t)MPAN * 32 * 2048;    // 8 panels x 8 x 4096 (hi only)
    bf16* wvkt    = w1v1t + (size_t)8 * 8 * 4096;       // 6 x 8 panels x 16 x 4096
    bf16* wdt     = wvkt + (size_t)6 * 8 * 16 * 4096;   // 12 panels x 16 x 4096

    // d_out doubles as m/p scratch (dead before final GEMM writes)
    float* pb = (float*)d_out;                          // [NN][512] f32
    bf16* mb  = (bf16*)(pb + (size_t)NN * 512);         // [NN][512] bf16
    float* out = (float*)d_out;

    hipMemsetAsync(deg_out, 0, 2 * 10240 * sizeof(int), stream);
    deg_kernel<<<(NE + 255) / 256, 256, 0, stream>>>(src, dst, deg_out, deg_in);
    scan_kernel<<<1, 1024, 0, stream>>>(deg_out, offsets, cursor);
    csr_kernel<<<(NE + 255) / 256, 256, 0, stream>>>(src, dst, deg_out, deg_in,
                                                     cursor, edge_dst, edge_w);

    // one-time conversions (B side stores hi plane only)
    split_rows<<<(NN * (INF / 4) + 255) / 256, 256, 0, stream>>>(x, bufA, NN, INF);
    tsplit<<<dim3((512 * (INF / 8) + 255) / 256, 1, 1), 256, 0, stream>>>(
        W1, w1v1t, INF, 512, 0, 0);
    tsplit<<<dim3((512 * (INF / 8) + 255) / 256, 1, 1), 256, 0, stream>>>(
        V1, w1v1t + (size_t)4 * 8 * 4096, INF, 512, 0, 0);
    tsplit<<<dim3((512 * (CH / 8) + 255) / 256, 1, 6), 256, 0, stream>>>(
        Wk, wvkt, CH, 512, (size_t)CH * 512, (size_t)8 * 16 * 4096);
    tsplit<<<dim3((512 * (CH / 8) + 255) / 256, 1, 6), 256, 0, stream>>>(
        Vk, wvkt + (size_t)4 * 16 * 4096, CH, 512, (size_t)CH * 512,
        (size_t)8 * 16 * 4096);
    tsplit<<<dim3((NL * (CH / 8) + 255) / 256, 1, 1), 256, 0, stream>>>(
        Wd, wdt, CH, NL, 0, 0);

    dim3 blk(256);
    int gwv = (MPAN / 2) * 8;     // 632 blocks (128-row tiles x 8 col-tiles)
    int gout = (MPAN / 2) * 12;   // 948 blocks

    // layer 1 (K = 256, KCh = 8)
    gemm_wv<<<gwv, blk, 0, stream>>>(bufA, w1v1t, mb, pb, NN, 8, 8);
    agg_fuse<<<NN, blk, 0, stream>>>(mb, pb, b1, offsets, edge_dst, edge_w, bufB);

    bf16* cur = bufB;
    bf16* nxt = bufA;
    for (int i = 0; i < 6; i++) {
        const bf16* WV = wvkt + (size_t)i * 8 * 16 * 4096;
        gemm_wv<<<gwv, blk, 0, stream>>>(cur, WV, mb, pb, NN, 16, 8);
        agg_fuse<<<NN, blk, 0, stream>>>(mb, pb, bk + (size_t)i * CH, offsets,
                                         edge_dst, edge_w, nxt);
        bf16* t = cur; cur = nxt; nxt = t;
    }

    // output: out = h @ Wd + bd  (K = 512, N = 1440)
    gemm_out<<<gout, blk, 0, stream>>>(cur, wdt, out, bd, NN, NL, 16, 12);
}